// Round 1
// baseline (1000.092 us; speedup 1.0000x reference)
//
#include <hip/hip_runtime.h>

typedef unsigned short u16;
typedef __attribute__((ext_vector_type(8))) short bf16x8;
typedef __attribute__((ext_vector_type(4))) float f32x4;

#define NB 64      // batch
#define NT 50      // time
#define NIN 256    // input dim
#define NH 2000    // hidden
#define HP 2048    // padded hidden
#define MR 3200    // NB*NT rows
#define EPS 1e-4f

__device__ __forceinline__ u16 f2bf(float f) {
  unsigned x = __float_as_uint(f);
  x += 0x7fffu + ((x >> 16) & 1u);
  return (u16)(x >> 16);
}

#define GLDS16(g, l) __builtin_amdgcn_global_load_lds( \
  (const __attribute__((address_space(1))) unsigned int*)(g), \
  (__attribute__((address_space(3))) unsigned int*)(l), 16, 0, 0)

// ---------------- converts (fp32 -> bf16, zero-padded) ----------------

// x: (3200,256) -> x16 same shape. 102400 threads, 8 elems each.
__global__ void cvt_x_kernel(const float* __restrict__ x, u16* __restrict__ x16) {
  int tid = blockIdx.x * 256 + threadIdx.x;
  const float* src = x + (size_t)tid * 8;
  float4 a = *(const float4*)src;
  float4 b = *(const float4*)(src + 4);
  union { u16 u[8]; uint4 v; } o;
  o.u[0]=f2bf(a.x); o.u[1]=f2bf(a.y); o.u[2]=f2bf(a.z); o.u[3]=f2bf(a.w);
  o.u[4]=f2bf(b.x); o.u[5]=f2bf(b.y); o.u[6]=f2bf(b.z); o.u[7]=f2bf(b.w);
  *(uint4*)(x16 + (size_t)tid * 8) = o.v;
}

// W0: (2000,256) -> (2048,256) bf16, rows >=2000 zero. 65536 threads.
__global__ void cvt_w0_kernel(const float* __restrict__ W0, u16* __restrict__ W16) {
  int tid = blockIdx.x * 256 + threadIdx.x;
  int r = tid >> 5;
  int c8 = (tid & 31) << 3;
  union { u16 u[8]; uint4 v; } o;
  if (r < NH) {
    const float* src = W0 + (size_t)r * NIN + c8;
    float4 a = *(const float4*)src;
    float4 b = *(const float4*)(src + 4);
    o.u[0]=f2bf(a.x); o.u[1]=f2bf(a.y); o.u[2]=f2bf(a.z); o.u[3]=f2bf(a.w);
    o.u[4]=f2bf(b.x); o.u[5]=f2bf(b.y); o.u[6]=f2bf(b.z); o.u[7]=f2bf(b.w);
  } else {
    o.v = make_uint4(0,0,0,0);
  }
  *(uint4*)(W16 + (size_t)tid * 8) = o.v;
}

// Ws: (10,2000,2000) -> (10,2048,2048) bf16, pad zero. 10*2048*256 threads.
__global__ void cvt_ws_kernel(const float* __restrict__ Ws, u16* __restrict__ W16) {
  int tid = blockIdx.x * 256 + threadIdx.x;
  int l  = tid >> 19;
  int r  = (tid >> 8) & 2047;
  int c8 = (tid & 255) << 3;
  union { u16 u[8]; uint4 v; } o;
  if (r < NH && c8 < NH) {
    const float* src = Ws + (size_t)l * (NH * NH) + (size_t)r * NH + c8;
    float4 a = *(const float4*)src;
    float4 b = *(const float4*)(src + 4);
    o.u[0]=f2bf(a.x); o.u[1]=f2bf(a.y); o.u[2]=f2bf(a.z); o.u[3]=f2bf(a.w);
    o.u[4]=f2bf(b.x); o.u[5]=f2bf(b.y); o.u[6]=f2bf(b.z); o.u[7]=f2bf(b.w);
  } else {
    o.v = make_uint4(0,0,0,0);
  }
  *(uint4*)(W16 + (size_t)tid * 8) = o.v;
}

// ---------------- GEMM: C(3200,2048 f32) = A(3200,K bf16) @ W(2048,K bf16)^T ----------------
// m97-style: 128x128 tile, BK=32, 4 waves of 64x64, global_load_lds width 16.
__global__ __launch_bounds__(256)
void gemm_kernel(const u16* __restrict__ A, const u16* __restrict__ W,
                 float* __restrict__ C, int K) {
  __shared__ u16 As[128 * 32];
  __shared__ u16 Bs[128 * 32];
  const int tid = threadIdx.x;
  const int w = tid >> 6, l = tid & 63;
  const int wr = w >> 1, wc = w & 1;
  const int bm = blockIdx.x, bn = blockIdx.y;
  f32x4 acc[4][4] = {};
  const u16* Ab = A + (size_t)bm * 128 * K;
  const u16* Wb = W + (size_t)bn * 128 * K;
  const int srow = tid >> 2;
  const int scol = (tid & 3) << 3;
  const size_t soff1 = (size_t)srow * K + scol;
  const size_t soff2 = (size_t)(srow + 64) * K + scol;
  u16* AsW = As + w * 512;
  u16* BsW = Bs + w * 512;
  const int lr = l & 15;
  const int lk = (l >> 4) << 3;
  const int nk = K >> 5;
  for (int ks = 0; ks < nk; ++ks) {
    const u16* ak = Ab + ks * 32;
    const u16* wk = Wb + ks * 32;
    __syncthreads();                     // protect LDS from previous iter's reads
    GLDS16(ak + soff1, AsW);
    GLDS16(ak + soff2, AsW + 2048);
    GLDS16(wk + soff1, BsW);
    GLDS16(wk + soff2, BsW + 2048);
    __syncthreads();                     // drain loads, publish LDS
    bf16x8 af[4], bfr[4];
#pragma unroll
    for (int i = 0; i < 4; ++i)
      af[i] = *(const bf16x8*)(As + (wr * 64 + i * 16 + lr) * 32 + lk);
#pragma unroll
    for (int j = 0; j < 4; ++j)
      bfr[j] = *(const bf16x8*)(Bs + (wc * 64 + j * 16 + lr) * 32 + lk);
#pragma unroll
    for (int i = 0; i < 4; ++i)
#pragma unroll
      for (int j = 0; j < 4; ++j)
        acc[i][j] = __builtin_amdgcn_mfma_f32_16x16x32_bf16(af[i], bfr[j], acc[i][j], 0, 0, 0);
  }
  const int lg = l >> 4;
  const int rbase = bm * 128 + wr * 64;
  const int cbase = bn * 128 + wc * 64;
#pragma unroll
  for (int i = 0; i < 4; ++i)
#pragma unroll
    for (int j = 0; j < 4; ++j) {
      int row0 = rbase + i * 16 + lg * 4;
      int col  = cbase + j * 16 + lr;
#pragma unroll
      for (int r = 0; r < 4; ++r)
        C[(size_t)(row0 + r) * HP + col] = acc[i][j][r];
    }
}

// ---------------- BN stats: mean/rstd per (t,h) over batch ----------------
__global__ void stats_kernel(const float* __restrict__ Mb, float* __restrict__ mean,
                             float* __restrict__ rstd) {
  int tid = blockIdx.x * 256 + threadIdx.x;   // 50*2048
  int t = tid >> 11, h = tid & 2047;
  const float* p = Mb + (size_t)t * HP + h;
  float s = 0.f, s2 = 0.f;
#pragma unroll 4
  for (int b = 0; b < NB; ++b) {
    float v = p[(size_t)b * (NT * HP)];
    s += v; s2 += v * v;
  }
  float mu = s * (1.f / NB);
  float var = fmaxf(s2 * (1.f / NB) - mu * mu, 0.f);
  mean[tid] = mu;
  rstd[tid] = rsqrtf(var + EPS);
}

// ---------------- BN apply + IndRNN scan + residual ----------------
// thread = (b,h). res may be null; out32 may be null (stride32 = row stride);
// out16 may be null (padded bf16 activation for next GEMM, pad cols zeroed).
__global__ void scan_kernel(const float* __restrict__ Mb, const float* __restrict__ mean,
                            const float* __restrict__ rstd, const float* __restrict__ u,
                            const float* __restrict__ g, const float* __restrict__ be,
                            const float* __restrict__ res, float* __restrict__ out32,
                            int stride32, u16* __restrict__ out16) {
  int tid = blockIdx.x * 256 + threadIdx.x;   // 64*2048
  int h = tid & 2047, b = tid >> 11;
  if (h >= NH) {
    if (out16) {
#pragma unroll 2
      for (int t = 0; t < NT; ++t)
        out16[(size_t)(b * NT + t) * HP + h] = 0;
    }
    return;
  }
  float uu = u[h], gg = g[h], bb = be[h];
  float hs = 0.f;
  for (int t = 0; t < NT; ++t) {
    size_t idx = (size_t)(b * NT + t) * HP + h;
    int th = t * HP + h;
    float v = (Mb[idx] - mean[th]) * rstd[th] * gg + bb;
    hs = fmaxf(fmaf(uu, hs, v), 0.f);
    float o = hs;
    if (res) o += res[idx];
    if (out32) out32[(size_t)(b * NT + t) * stride32 + h] = o;
    if (out16) out16[idx] = f2bf(o);
  }
}

// ---------------- orchestration ----------------
extern "C" void kernel_launch(void* const* d_in, const int* in_sizes, int n_in,
                              void* d_out, int out_size, void* d_ws, size_t ws_size,
                              hipStream_t stream) {
  const float* x   = (const float*)d_in[0];
  const float* W0  = (const float*)d_in[1];
  // d_in[2] = b0 (cancels in BN)
  const float* u0  = (const float*)d_in[3];
  const float* g0  = (const float*)d_in[4];
  const float* be0 = (const float*)d_in[5];
  const float* Ws  = (const float*)d_in[6];
  // d_in[7] = bs (cancels in BN)
  const float* us  = (const float*)d_in[8];
  const float* gs  = (const float*)d_in[9];
  const float* bes = (const float*)d_in[10];
  float* out = (float*)d_out;

  char* ws = (char*)d_ws;
  u16*   x16  = (u16*)  (ws + 0);           // 3200*256*2      = 1,638,400
  u16*   W016 = (u16*)  (ws + 1638400);     // 2048*256*2      = 1,048,576
  u16*   Ws16 = (u16*)  (ws + 2686976);     // 10*2048*2048*2  = 83,886,080
  float* Mbuf = (float*)(ws + 86573056);    // 3200*2048*4     = 26,214,400
  float* A32  = (float*)(ws + 112787456);   // 3200*2048*4     = 26,214,400
  u16*   A16  = (u16*)  (ws + 139001856);   // 3200*2048*2     = 13,107,200
  u16*   B16  = (u16*)  (ws + 152109056);   // 3200*2048*2     = 13,107,200
  float* mean = (float*)(ws + 165216256);   // 50*2048*4       = 409,600
  float* rstd = (float*)(ws + 165625856);   // 50*2048*4       = 409,600

  // converts
  cvt_x_kernel <<<400,   256, 0, stream>>>(x, x16);
  cvt_w0_kernel<<<256,   256, 0, stream>>>(W0, W016);
  cvt_ws_kernel<<<20480, 256, 0, stream>>>(Ws, Ws16);

  dim3 ggrid(25, 16);

  // stem layer: x @ W0^T, K=256
  gemm_kernel <<<ggrid, 256, 0, stream>>>(x16, W016, Mbuf, NIN);
  stats_kernel<<<400,   256, 0, stream>>>(Mbuf, mean, rstd);
  scan_kernel <<<512,   256, 0, stream>>>(Mbuf, mean, rstd, u0, g0, be0,
                                          nullptr, A32, HP, A16);

  for (int l = 0; l < 10; ++l) {
    const u16* Ain = (l & 1) ? B16 : A16;
    gemm_kernel <<<ggrid, 256, 0, stream>>>(Ain, Ws16 + (size_t)l * HP * HP, Mbuf, HP);
    stats_kernel<<<400,   256, 0, stream>>>(Mbuf, mean, rstd);
    const float* ul  = us  + (size_t)l * NH;
    const float* gl  = gs  + (size_t)l * NH;
    const float* bel = bes + (size_t)l * NH;
    if ((l & 1) == 0) {
      // first of pair: only bf16 activation needed for next GEMM
      scan_kernel<<<512, 256, 0, stream>>>(Mbuf, mean, rstd, ul, gl, bel,
                                           nullptr, nullptr, 0, B16);
    } else if (l < 9) {
      // second of pair: add residual (A32), produce new A32 + A16
      scan_kernel<<<512, 256, 0, stream>>>(Mbuf, mean, rstd, ul, gl, bel,
                                           A32, A32, HP, A16);
    } else {
      // last layer: add residual, write final output (stride 2000)
      scan_kernel<<<512, 256, 0, stream>>>(Mbuf, mean, rstd, ul, gl, bel,
                                           A32, out, NH, nullptr);
    }
  }
}

// Round 2
// 885.467 us; speedup vs baseline: 1.1295x; 1.1295x over previous
//
#include <hip/hip_runtime.h>

typedef unsigned short u16;
typedef __attribute__((ext_vector_type(8))) short bf16x8;
typedef __attribute__((ext_vector_type(4))) float f32x4;

#define NB 64      // batch
#define NT 50      // time
#define NIN 256    // input dim
#define NH 2000    // hidden
#define HP 2048    // padded hidden
#define EPS 1e-4f

__device__ __forceinline__ u16 f2bf(float f) {
  unsigned x = __float_as_uint(f);
  x += 0x7fffu + ((x >> 16) & 1u);
  return (u16)(x >> 16);
}

#define GLDS16(g, l) __builtin_amdgcn_global_load_lds( \
  (const __attribute__((address_space(1))) unsigned int*)(g), \
  (__attribute__((address_space(3))) unsigned int*)(l), 16, 0, 0)

// ---------------- converts (fp32 -> bf16, zero-padded) ----------------

// x: (B,T,IN) b-major -> x16 (3200,256) t-major rows (row = t*64+b).
__global__ void cvt_x_kernel(const float* __restrict__ x, u16* __restrict__ x16) {
  int tid = blockIdx.x * 256 + threadIdx.x;   // 102400
  int row = tid >> 5;                          // t*64+b
  int c8  = (tid & 31) << 3;
  int t = row >> 6, b = row & 63;
  const float* src = x + (size_t)(b * NT + t) * NIN + c8;
  float4 a = *(const float4*)src;
  float4 c = *(const float4*)(src + 4);
  union { u16 u[8]; uint4 v; } o;
  o.u[0]=f2bf(a.x); o.u[1]=f2bf(a.y); o.u[2]=f2bf(a.z); o.u[3]=f2bf(a.w);
  o.u[4]=f2bf(c.x); o.u[5]=f2bf(c.y); o.u[6]=f2bf(c.z); o.u[7]=f2bf(c.w);
  *(uint4*)(x16 + (size_t)row * NIN + c8) = o.v;
}

// W0: (2000,256) -> (2048,256) bf16, rows >=2000 zero. 65536 threads.
__global__ void cvt_w0_kernel(const float* __restrict__ W0, u16* __restrict__ W16) {
  int tid = blockIdx.x * 256 + threadIdx.x;
  int r = tid >> 5;
  int c8 = (tid & 31) << 3;
  union { u16 u[8]; uint4 v; } o;
  if (r < NH) {
    const float* src = W0 + (size_t)r * NIN + c8;
    float4 a = *(const float4*)src;
    float4 b = *(const float4*)(src + 4);
    o.u[0]=f2bf(a.x); o.u[1]=f2bf(a.y); o.u[2]=f2bf(a.z); o.u[3]=f2bf(a.w);
    o.u[4]=f2bf(b.x); o.u[5]=f2bf(b.y); o.u[6]=f2bf(b.z); o.u[7]=f2bf(b.w);
  } else {
    o.v = make_uint4(0,0,0,0);
  }
  *(uint4*)(W16 + (size_t)tid * 8) = o.v;
}

// Ws: (10,2000,2000) -> (10,2048,2048) bf16, pad zero.
__global__ void cvt_ws_kernel(const float* __restrict__ Ws, u16* __restrict__ W16) {
  int tid = blockIdx.x * 256 + threadIdx.x;
  int l  = tid >> 19;
  int r  = (tid >> 8) & 2047;
  int c8 = (tid & 255) << 3;
  union { u16 u[8]; uint4 v; } o;
  if (r < NH && c8 < NH) {
    const float* src = Ws + (size_t)l * (NH * NH) + (size_t)r * NH + c8;
    float4 a = *(const float4*)src;
    float4 b = *(const float4*)(src + 4);
    o.u[0]=f2bf(a.x); o.u[1]=f2bf(a.y); o.u[2]=f2bf(a.z); o.u[3]=f2bf(a.w);
    o.u[4]=f2bf(b.x); o.u[5]=f2bf(b.y); o.u[6]=f2bf(b.z); o.u[7]=f2bf(b.w);
  } else {
    o.v = make_uint4(0,0,0,0);
  }
  *(uint4*)(W16 + (size_t)tid * 8) = o.v;
}

// ---------------- GEMM + fused BatchNorm ----------------
// C(3200,2048) = A(3200,K bf16, t-major rows) @ W(2048,K bf16)^T
// 128x128 tile (= timestep pair x 128 h), BK=64, 4 waves as 2x2 (64x64 each).
// Wave-row wr == one timestep, all 64 batch rows -> BN stats wave-local.
// Writes NORMALIZED f32 M (pad cols h>=2000 forced to 0).
__global__ __launch_bounds__(256)
void gemm_bn_kernel(const u16* __restrict__ A, const u16* __restrict__ W,
                    float* __restrict__ Mn, const float* __restrict__ g,
                    const float* __restrict__ be, int K) {
  __shared__ u16 As[128 * 64];
  __shared__ u16 Bs[128 * 64];
  const int tid = threadIdx.x;
  const int w = tid >> 6, l = tid & 63;
  const int wr = w >> 1, wc = w & 1;
  const int bm = blockIdx.x, bn = blockIdx.y;
  f32x4 acc[4][4] = {};
  const u16* Ab = A + (size_t)bm * 128 * K;
  const u16* Wb = W + (size_t)bn * 128 * K;
  // staging: wave w stages rows w*32..w*32+31 of each tile; 4 loads of 8 rows
  const int srow = (w << 5) + (l >> 3);
  const int scol = (l & 7) << 3;
  const size_t goff = (size_t)srow * K + scol;
  u16* AsW = As + (w << 5) * 64;   // wave-uniform LDS base
  u16* BsW = Bs + (w << 5) * 64;
  const int lr = l & 15;
  const int lk = (l >> 4) << 3;
  const int nk = K >> 6;
  for (int ks = 0; ks < nk; ++ks) {
    const u16* ak = Ab + ks * 64 + goff;
    const u16* wk = Wb + ks * 64 + goff;
    __syncthreads();                  // protect LDS from previous iter's reads
    GLDS16(ak,            AsW);
    GLDS16(ak + 8  * K,   AsW + 8  * 64);
    GLDS16(ak + 16 * K,   AsW + 16 * 64);
    GLDS16(ak + 24 * K,   AsW + 24 * 64);
    GLDS16(wk,            BsW);
    GLDS16(wk + 8  * K,   BsW + 8  * 64);
    GLDS16(wk + 16 * K,   BsW + 16 * 64);
    GLDS16(wk + 24 * K,   BsW + 24 * 64);
    __syncthreads();                  // drain loads, publish LDS
#pragma unroll
    for (int kk = 0; kk < 2; ++kk) {
      bf16x8 af[4], bfr[4];
#pragma unroll
      for (int i = 0; i < 4; ++i)
        af[i] = *(const bf16x8*)(As + (wr * 64 + i * 16 + lr) * 64 + kk * 32 + lk);
#pragma unroll
      for (int j = 0; j < 4; ++j)
        bfr[j] = *(const bf16x8*)(Bs + (wc * 64 + j * 16 + lr) * 64 + kk * 32 + lk);
#pragma unroll
      for (int i = 0; i < 4; ++i)
#pragma unroll
        for (int j = 0; j < 4; ++j)
          acc[i][j] = __builtin_amdgcn_mfma_f32_16x16x32_bf16(af[i], bfr[j], acc[i][j], 0, 0, 0);
    }
  }
  // ---- fused BN epilogue: stats over the wave's 64 rows (= full batch of one t)
  const int lg = l >> 4;
  const int rbase = bm * 128 + wr * 64;
  const int cbase = bn * 128 + wc * 64;
#pragma unroll
  for (int j = 0; j < 4; ++j) {
    float s = 0.f, s2 = 0.f;
#pragma unroll
    for (int i = 0; i < 4; ++i)
#pragma unroll
      for (int r = 0; r < 4; ++r) { float v = acc[i][j][r]; s += v; s2 += v * v; }
    s  += __shfl_xor(s, 16);  s2 += __shfl_xor(s2, 16);
    s  += __shfl_xor(s, 32);  s2 += __shfl_xor(s2, 32);
    float mu  = s * (1.f / 64.f);
    float var = fmaxf(s2 * (1.f / 64.f) - mu * mu, 0.f);
    int col = cbase + j * 16 + lr;
    bool ok = col < NH;
    float gg = ok ? g[col]  : 0.f;
    float bb = ok ? be[col] : 0.f;
    float sc = rsqrtf(var + EPS) * gg;
#pragma unroll
    for (int i = 0; i < 4; ++i) {
      int row0 = rbase + i * 16 + lg * 4;
#pragma unroll
      for (int r = 0; r < 4; ++r)
        Mn[(size_t)(row0 + r) * HP + col] = (acc[i][j][r] - mu) * sc + bb;
    }
  }
}

// ---------------- IndRNN scan + residual (reads normalized M, t-major) ----------------
__global__ void scan_kernel(const float* __restrict__ Mn, const float* __restrict__ u,
                            const float* __restrict__ res, float* __restrict__ out32,
                            int bmajor, u16* __restrict__ out16) {
  int tid = blockIdx.x * 256 + threadIdx.x;   // 64*2048
  int h = tid & 2047, b = tid >> 11;
  if (h >= NH) {
    if (out16) {
#pragma unroll 2
      for (int t = 0; t < NT; ++t)
        out16[(size_t)(t * NB + b) * HP + h] = 0;
    }
    return;
  }
  float uu = u[h];
  float hs = 0.f;
  for (int t = 0; t < NT; ++t) {
    size_t idx = (size_t)(t * NB + b) * HP + h;
    float v = Mn[idx];
    hs = fmaxf(fmaf(uu, hs, v), 0.f);
    float o = hs;
    if (res) o += res[idx];
    if (out32) {
      if (bmajor) out32[(size_t)(b * NT + t) * NH + h] = o;  // final output layout
      else        out32[idx] = o;                             // t-major f32
    }
    if (out16) out16[idx] = f2bf(o);
  }
}

// ---------------- orchestration ----------------
extern "C" void kernel_launch(void* const* d_in, const int* in_sizes, int n_in,
                              void* d_out, int out_size, void* d_ws, size_t ws_size,
                              hipStream_t stream) {
  const float* x   = (const float*)d_in[0];
  const float* W0  = (const float*)d_in[1];
  // d_in[2] = b0 (cancels in BN)
  const float* u0  = (const float*)d_in[3];
  const float* g0  = (const float*)d_in[4];
  const float* be0 = (const float*)d_in[5];
  const float* Ws  = (const float*)d_in[6];
  // d_in[7] = bs (cancels in BN)
  const float* us  = (const float*)d_in[8];
  const float* gs  = (const float*)d_in[9];
  const float* bes = (const float*)d_in[10];
  float* out = (float*)d_out;

  char* ws = (char*)d_ws;
  u16*   x16  = (u16*)  (ws + 0);           // 3200*256*2      = 1,638,400
  u16*   W016 = (u16*)  (ws + 1638400);     // 2048*256*2      = 1,048,576
  u16*   Ws16 = (u16*)  (ws + 2686976);     // 10*2048*2048*2  = 83,886,080
  float* Mbuf = (float*)(ws + 86573056);    // 3200*2048*4     = 26,214,400
  float* A32  = (float*)(ws + 112787456);   // 3200*2048*4     = 26,214,400
  u16*   A16  = (u16*)  (ws + 139001856);   // 3200*2048*2     = 13,107,200
  u16*   B16  = (u16*)  (ws + 152109056);   // 3200*2048*2     = 13,107,200

  // converts
  cvt_x_kernel <<<400,   256, 0, stream>>>(x, x16);
  cvt_w0_kernel<<<256,   256, 0, stream>>>(W0, W016);
  cvt_ws_kernel<<<20480, 256, 0, stream>>>(Ws, Ws16);

  dim3 ggrid(25, 16);

  // stem layer: x @ W0^T, K=256, fused BN
  gemm_bn_kernel<<<ggrid, 256, 0, stream>>>(x16, W016, Mbuf, g0, be0, NIN);
  scan_kernel   <<<512,   256, 0, stream>>>(Mbuf, u0, nullptr, A32, 0, A16);

  for (int l = 0; l < 10; ++l) {
    const u16* Ain = (l & 1) ? B16 : A16;
    gemm_bn_kernel<<<ggrid, 256, 0, stream>>>(Ain, Ws16 + (size_t)l * HP * HP, Mbuf,
                                              gs + (size_t)l * NH, bes + (size_t)l * NH, HP);
    const float* ul = us + (size_t)l * NH;
    if ((l & 1) == 0) {
      // first of pair: only bf16 activation needed for next GEMM
      scan_kernel<<<512, 256, 0, stream>>>(Mbuf, ul, nullptr, nullptr, 0, B16);
    } else if (l < 9) {
      // second of pair: add residual (A32), produce new A32 + A16
      scan_kernel<<<512, 256, 0, stream>>>(Mbuf, ul, A32, A32, 0, A16);
    } else {
      // last layer: add residual, write final output (b-major, stride 2000)
      scan_kernel<<<512, 256, 0, stream>>>(Mbuf, ul, A32, out, 1, nullptr);
    }
  }
}

// Round 3
// 875.409 us; speedup vs baseline: 1.1424x; 1.0115x over previous
//
#include <hip/hip_runtime.h>

typedef unsigned short u16;
typedef __attribute__((ext_vector_type(8))) short bf16x8;
typedef __attribute__((ext_vector_type(4))) float f32x4;

#define NB 64      // batch
#define NT 50      // time
#define NIN 256    // input dim
#define NH 2000    // hidden
#define HP 2048    // padded hidden
#define EPS 1e-4f

__device__ __forceinline__ u16 f2bf(float f) {
  unsigned x = __float_as_uint(f);
  x += 0x7fffu + ((x >> 16) & 1u);
  return (u16)(x >> 16);
}
__device__ __forceinline__ float bf2f(u16 u) {
  return __uint_as_float(((unsigned)u) << 16);
}

#define GLDS16(g, l) __builtin_amdgcn_global_load_lds( \
  (const __attribute__((address_space(1))) unsigned int*)(g), \
  (__attribute__((address_space(3))) unsigned int*)(l), 16, 0, 0)

// ---------------- converts (fp32 -> bf16, zero-padded) ----------------

// x: (B,T,IN) b-major -> x16 (3200,256) t-major rows (row = t*64+b).
__global__ void cvt_x_kernel(const float* __restrict__ x, u16* __restrict__ x16) {
  int tid = blockIdx.x * 256 + threadIdx.x;   // 102400
  int row = tid >> 5;                          // t*64+b
  int c8  = (tid & 31) << 3;
  int t = row >> 6, b = row & 63;
  const float* src = x + (size_t)(b * NT + t) * NIN + c8;
  float4 a = *(const float4*)src;
  float4 c = *(const float4*)(src + 4);
  union { u16 u[8]; uint4 v; } o;
  o.u[0]=f2bf(a.x); o.u[1]=f2bf(a.y); o.u[2]=f2bf(a.z); o.u[3]=f2bf(a.w);
  o.u[4]=f2bf(c.x); o.u[5]=f2bf(c.y); o.u[6]=f2bf(c.z); o.u[7]=f2bf(c.w);
  *(uint4*)(x16 + (size_t)row * NIN + c8) = o.v;
}

// W0: (2000,256) -> (2048,256) bf16, rows >=2000 zero.
__global__ void cvt_w0_kernel(const float* __restrict__ W0, u16* __restrict__ W16) {
  int tid = blockIdx.x * 256 + threadIdx.x;
  int r = tid >> 5;
  int c8 = (tid & 31) << 3;
  union { u16 u[8]; uint4 v; } o;
  if (r < NH) {
    const float* src = W0 + (size_t)r * NIN + c8;
    float4 a = *(const float4*)src;
    float4 b = *(const float4*)(src + 4);
    o.u[0]=f2bf(a.x); o.u[1]=f2bf(a.y); o.u[2]=f2bf(a.z); o.u[3]=f2bf(a.w);
    o.u[4]=f2bf(b.x); o.u[5]=f2bf(b.y); o.u[6]=f2bf(b.z); o.u[7]=f2bf(b.w);
  } else {
    o.v = make_uint4(0,0,0,0);
  }
  *(uint4*)(W16 + (size_t)tid * 8) = o.v;
}

// Ws: (10,2000,2000) -> (10,2048,2048) bf16, pad zero.
__global__ void cvt_ws_kernel(const float* __restrict__ Ws, u16* __restrict__ W16) {
  int tid = blockIdx.x * 256 + threadIdx.x;
  int l  = tid >> 19;
  int r  = (tid >> 8) & 2047;
  int c8 = (tid & 255) << 3;
  union { u16 u[8]; uint4 v; } o;
  if (r < NH && c8 < NH) {
    const float* src = Ws + (size_t)l * (NH * NH) + (size_t)r * NH + c8;
    float4 a = *(const float4*)src;
    float4 b = *(const float4*)(src + 4);
    o.u[0]=f2bf(a.x); o.u[1]=f2bf(a.y); o.u[2]=f2bf(a.z); o.u[3]=f2bf(a.w);
    o.u[4]=f2bf(b.x); o.u[5]=f2bf(b.y); o.u[6]=f2bf(b.z); o.u[7]=f2bf(b.w);
  } else {
    o.v = make_uint4(0,0,0,0);
  }
  *(uint4*)(W16 + (size_t)tid * 8) = o.v;
}

// ---------------- GEMM + fused BatchNorm (double-buffered LDS) ----------------
// C(3200,2048) = A(3200,K bf16, t-major rows) @ W(2048,K bf16)^T
// 128x128 tile, BK=64, 4 waves as 2x2 (64x64 each). Wave-row == one timestep
// -> BN stats wave-local. Writes NORMALIZED bf16 M (pad cols h>=2000 -> 0).
// Pipeline: STAGE(next buf) issued before ds_read+MFMA(cur buf); one
// __syncthreads() per K-step (its implicit vmcnt(0)+lgkmcnt(0) drain is the
// publish point: readers of the buffer being staged drained lgkm before the
// PREVIOUS barrier; loads staged this iter drain at THIS barrier).
__global__ __launch_bounds__(256)
void gemm_bn_kernel(const u16* __restrict__ A, const u16* __restrict__ W,
                    u16* __restrict__ Mn, const float* __restrict__ g,
                    const float* __restrict__ be, int K) {
  __shared__ u16 As[2 * 128 * 64];
  __shared__ u16 Bs[2 * 128 * 64];
  const int tid = threadIdx.x;
  const int w = tid >> 6, l = tid & 63;
  const int wr = w >> 1, wc = w & 1;
  const int bm = blockIdx.x, bn = blockIdx.y;
  f32x4 acc[4][4] = {};
  const u16* Ab = A + (size_t)bm * 128 * K;
  const u16* Wb = W + (size_t)bn * 128 * K;
  // staging: wave w stages rows w*32..w*32+31 of each tile (4 loads of 8 rows)
  const int srow = (w << 5) + (l >> 3);
  const int scol = (l & 7) << 3;
  const size_t goff = (size_t)srow * K + scol;
  const int wbase = (w << 5) * 64;       // wave-uniform LDS offset (u16 units)
  const int lr = l & 15;
  const int lk = (l >> 4) << 3;
  const int nk = K >> 6;

  // prologue: stage ks=0 into buf 0
  {
    const u16* ak = Ab + goff;
    const u16* wk = Wb + goff;
    GLDS16(ak,          As + wbase);
    GLDS16(ak + 8 * K,  As + wbase + 8 * 64);
    GLDS16(ak + 16 * K, As + wbase + 16 * 64);
    GLDS16(ak + 24 * K, As + wbase + 24 * 64);
    GLDS16(wk,          Bs + wbase);
    GLDS16(wk + 8 * K,  Bs + wbase + 8 * 64);
    GLDS16(wk + 16 * K, Bs + wbase + 16 * 64);
    GLDS16(wk + 24 * K, Bs + wbase + 24 * 64);
  }
  __syncthreads();

  int cur = 0;
  for (int ks = 0; ks < nk; ++ks) {
    // issue next tile's staging first (into the other buffer)
    if (ks + 1 < nk) {
      const int nb = (cur ^ 1) * (128 * 64);
      const u16* ak = Ab + (ks + 1) * 64 + goff;
      const u16* wk = Wb + (ks + 1) * 64 + goff;
      GLDS16(ak,          As + nb + wbase);
      GLDS16(ak + 8 * K,  As + nb + wbase + 8 * 64);
      GLDS16(ak + 16 * K, As + nb + wbase + 16 * 64);
      GLDS16(ak + 24 * K, As + nb + wbase + 24 * 64);
      GLDS16(wk,          Bs + nb + wbase);
      GLDS16(wk + 8 * K,  Bs + nb + wbase + 8 * 64);
      GLDS16(wk + 16 * K, Bs + nb + wbase + 16 * 64);
      GLDS16(wk + 24 * K, Bs + nb + wbase + 24 * 64);
    }
    // compute on current buffer
    const int cb = cur * (128 * 64);
#pragma unroll
    for (int kk = 0; kk < 2; ++kk) {
      bf16x8 af[4], bfr[4];
#pragma unroll
      for (int i = 0; i < 4; ++i)
        af[i] = *(const bf16x8*)(As + cb + (wr * 64 + i * 16 + lr) * 64 + kk * 32 + lk);
#pragma unroll
      for (int j = 0; j < 4; ++j)
        bfr[j] = *(const bf16x8*)(Bs + cb + (wc * 64 + j * 16 + lr) * 64 + kk * 32 + lk);
#pragma unroll
      for (int i = 0; i < 4; ++i)
#pragma unroll
        for (int j = 0; j < 4; ++j)
          acc[i][j] = __builtin_amdgcn_mfma_f32_16x16x32_bf16(af[i], bfr[j], acc[i][j], 0, 0, 0);
    }
    __syncthreads();   // drains vmcnt(0)+lgkmcnt(0): publishes next buf, retires reads
    cur ^= 1;
  }

  // ---- fused BN epilogue: stats over the wave's 64 rows (= full batch of one t)
  const int lg = l >> 4;
  const int rbase = bm * 128 + wr * 64;
  const int cbase = bn * 128 + wc * 64;
#pragma unroll
  for (int j = 0; j < 4; ++j) {
    float s = 0.f, s2 = 0.f;
#pragma unroll
    for (int i = 0; i < 4; ++i)
#pragma unroll
      for (int r = 0; r < 4; ++r) { float v = acc[i][j][r]; s += v; s2 += v * v; }
    s  += __shfl_xor(s, 16);  s2 += __shfl_xor(s2, 16);
    s  += __shfl_xor(s, 32);  s2 += __shfl_xor(s2, 32);
    float mu  = s * (1.f / 64.f);
    float var = fmaxf(s2 * (1.f / 64.f) - mu * mu, 0.f);
    int col = cbase + j * 16 + lr;
    bool ok = col < NH;
    float gg = ok ? g[col]  : 0.f;
    float bb = ok ? be[col] : 0.f;
    float sc = rsqrtf(var + EPS) * gg;
#pragma unroll
    for (int i = 0; i < 4; ++i) {
      int row0 = rbase + i * 16 + lg * 4;
#pragma unroll
      for (int r = 0; r < 4; ++r)
        Mn[(size_t)(row0 + r) * HP + col] = f2bf((acc[i][j][r] - mu) * sc + bb);
    }
  }
}

// ---------------- IndRNN scan + residual (reads normalized bf16 M, t-major) ----------------
// thread = (b, h-pair). 65536 threads.
__global__ void scan_kernel(const u16* __restrict__ Mn, const float* __restrict__ u,
                            const float* __restrict__ res, float* __restrict__ out32,
                            int bmajor, u16* __restrict__ out16) {
  int tid = blockIdx.x * 256 + threadIdx.x;   // 64*1024
  int h2 = tid & 1023, b = tid >> 10;
  int h = h2 << 1;
  if (h >= NH) {
    if (out16) {
#pragma unroll 2
      for (int t = 0; t < NT; ++t)
        *(unsigned*)(out16 + (size_t)(t * NB + b) * HP + h) = 0u;
    }
    return;
  }
  float2 uu = *(const float2*)(u + h);
  float h0 = 0.f, h1 = 0.f;
  for (int t = 0; t < NT; ++t) {
    size_t idx = (size_t)(t * NB + b) * HP + h;
    unsigned mv = *(const unsigned*)(Mn + idx);
    float v0 = bf2f((u16)(mv & 0xffffu));
    float v1 = bf2f((u16)(mv >> 16));
    h0 = fmaxf(fmaf(uu.x, h0, v0), 0.f);
    h1 = fmaxf(fmaf(uu.y, h1, v1), 0.f);
    float o0 = h0, o1 = h1;
    if (res) {
      float2 rv = *(const float2*)(res + idx);
      o0 += rv.x; o1 += rv.y;
    }
    if (out32) {
      if (bmajor) {
        float2 ov = make_float2(o0, o1);
        *(float2*)(out32 + (size_t)(b * NT + t) * NH + h) = ov;
      } else {
        float2 ov = make_float2(o0, o1);
        *(float2*)(out32 + idx) = ov;
      }
    }
    if (out16) {
      unsigned pv = (unsigned)f2bf(o0) | ((unsigned)f2bf(o1) << 16);
      *(unsigned*)(out16 + idx) = pv;
    }
  }
}

// ---------------- orchestration ----------------
extern "C" void kernel_launch(void* const* d_in, const int* in_sizes, int n_in,
                              void* d_out, int out_size, void* d_ws, size_t ws_size,
                              hipStream_t stream) {
  const float* x   = (const float*)d_in[0];
  const float* W0  = (const float*)d_in[1];
  // d_in[2] = b0 (cancels in BN)
  const float* u0  = (const float*)d_in[3];
  const float* g0  = (const float*)d_in[4];
  const float* be0 = (const float*)d_in[5];
  const float* Ws  = (const float*)d_in[6];
  // d_in[7] = bs (cancels in BN)
  const float* us  = (const float*)d_in[8];
  const float* gs  = (const float*)d_in[9];
  const float* bes = (const float*)d_in[10];
  float* out = (float*)d_out;

  char* ws = (char*)d_ws;
  u16*   x16  = (u16*)  (ws + 0);           // 3200*256*2      = 1,638,400
  u16*   W016 = (u16*)  (ws + 1638400);     // 2048*256*2      = 1,048,576
  u16*   Ws16 = (u16*)  (ws + 2686976);     // 10*2048*2048*2  = 83,886,080
  u16*   Mbuf = (u16*)  (ws + 86573056);    // 3200*2048*2     = 13,107,200
  float* A32  = (float*)(ws + 99680256);    // 3200*2048*4     = 26,214,400
  u16*   A16  = (u16*)  (ws + 125894656);   // 3200*2048*2     = 13,107,200
  u16*   B16  = (u16*)  (ws + 139001856);   // 3200*2048*2     = 13,107,200

  // converts
  cvt_x_kernel <<<400,   256, 0, stream>>>(x, x16);
  cvt_w0_kernel<<<256,   256, 0, stream>>>(W0, W016);
  cvt_ws_kernel<<<20480, 256, 0, stream>>>(Ws, Ws16);

  dim3 ggrid(25, 16);

  // stem layer: x @ W0^T, K=256, fused BN
  gemm_bn_kernel<<<ggrid, 256, 0, stream>>>(x16, W016, Mbuf, g0, be0, NIN);
  scan_kernel   <<<256,   256, 0, stream>>>(Mbuf, u0, nullptr, A32, 0, A16);

  for (int l = 0; l < 10; ++l) {
    const u16* Ain = (l & 1) ? B16 : A16;
    gemm_bn_kernel<<<ggrid, 256, 0, stream>>>(Ain, Ws16 + (size_t)l * HP * HP, Mbuf,
                                              gs + (size_t)l * NH, bes + (size_t)l * NH, HP);
    const float* ul = us + (size_t)l * NH;
    if ((l & 1) == 0) {
      // first of pair: only bf16 activation needed for next GEMM
      scan_kernel<<<256, 256, 0, stream>>>(Mbuf, ul, nullptr, nullptr, 0, B16);
    } else if (l < 9) {
      // second of pair: add residual (A32), produce new A32 + A16
      scan_kernel<<<256, 256, 0, stream>>>(Mbuf, ul, A32, A32, 0, A16);
    } else {
      // last layer: add residual, write final output (b-major, stride 2000)
      scan_kernel<<<256, 256, 0, stream>>>(Mbuf, ul, A32, out, 1, nullptr);
    }
  }
}

// Round 4
// 838.662 us; speedup vs baseline: 1.1925x; 1.0438x over previous
//
#include <hip/hip_runtime.h>

typedef unsigned short u16;
typedef __attribute__((ext_vector_type(8))) short bf16x8;
typedef __attribute__((ext_vector_type(4))) float f32x4;

#define NB 64      // batch
#define NT 50      // time
#define NIN 256    // input dim
#define NH 2000    // hidden
#define HP 2048    // padded hidden
#define EPS 1e-4f

__device__ __forceinline__ u16 f2bf(float f) {
  unsigned x = __float_as_uint(f);
  x += 0x7fffu + ((x >> 16) & 1u);
  return (u16)(x >> 16);
}
__device__ __forceinline__ float bf2f(u16 u) {
  return __uint_as_float(((unsigned)u) << 16);
}

#define GLDS16(g, l) __builtin_amdgcn_global_load_lds( \
  (const __attribute__((address_space(1))) unsigned int*)(g), \
  (__attribute__((address_space(3))) unsigned int*)(l), 16, 0, 0)

// ---------------- converts (fp32 -> bf16, zero-padded) ----------------

// x: (B,T,IN) b-major -> x16 (3200,256) t-major rows (row = t*64+b).
__global__ void cvt_x_kernel(const float* __restrict__ x, u16* __restrict__ x16) {
  int tid = blockIdx.x * 256 + threadIdx.x;   // 102400
  int row = tid >> 5;                          // t*64+b
  int c8  = (tid & 31) << 3;
  int t = row >> 6, b = row & 63;
  const float* src = x + (size_t)(b * NT + t) * NIN + c8;
  float4 a = *(const float4*)src;
  float4 c = *(const float4*)(src + 4);
  union { u16 u[8]; uint4 v; } o;
  o.u[0]=f2bf(a.x); o.u[1]=f2bf(a.y); o.u[2]=f2bf(a.z); o.u[3]=f2bf(a.w);
  o.u[4]=f2bf(c.x); o.u[5]=f2bf(c.y); o.u[6]=f2bf(c.z); o.u[7]=f2bf(c.w);
  *(uint4*)(x16 + (size_t)row * NIN + c8) = o.v;
}

// W0: (2000,256) -> (2048,256) bf16, rows >=2000 zero.
__global__ void cvt_w0_kernel(const float* __restrict__ W0, u16* __restrict__ W16) {
  int tid = blockIdx.x * 256 + threadIdx.x;
  int r = tid >> 5;
  int c8 = (tid & 31) << 3;
  union { u16 u[8]; uint4 v; } o;
  if (r < NH) {
    const float* src = W0 + (size_t)r * NIN + c8;
    float4 a = *(const float4*)src;
    float4 b = *(const float4*)(src + 4);
    o.u[0]=f2bf(a.x); o.u[1]=f2bf(a.y); o.u[2]=f2bf(a.z); o.u[3]=f2bf(a.w);
    o.u[4]=f2bf(b.x); o.u[5]=f2bf(b.y); o.u[6]=f2bf(b.z); o.u[7]=f2bf(b.w);
  } else {
    o.v = make_uint4(0,0,0,0);
  }
  *(uint4*)(W16 + (size_t)tid * 8) = o.v;
}

// Ws: (10,2000,2000) -> (10,2048,2048) bf16, pad zero.
__global__ void cvt_ws_kernel(const float* __restrict__ Ws, u16* __restrict__ W16) {
  int tid = blockIdx.x * 256 + threadIdx.x;
  int l  = tid >> 19;
  int r  = (tid >> 8) & 2047;
  int c8 = (tid & 255) << 3;
  union { u16 u[8]; uint4 v; } o;
  if (r < NH && c8 < NH) {
    const float* src = Ws + (size_t)l * (NH * NH) + (size_t)r * NH + c8;
    float4 a = *(const float4*)src;
    float4 b = *(const float4*)(src + 4);
    o.u[0]=f2bf(a.x); o.u[1]=f2bf(a.y); o.u[2]=f2bf(a.z); o.u[3]=f2bf(a.w);
    o.u[4]=f2bf(b.x); o.u[5]=f2bf(b.y); o.u[6]=f2bf(b.z); o.u[7]=f2bf(b.w);
  } else {
    o.v = make_uint4(0,0,0,0);
  }
  *(uint4*)(W16 + (size_t)tid * 8) = o.v;
}

// ---------------- GEMM + fused BatchNorm (triple-buffered, counted vmcnt) ----------------
// C(3200,2048) = A(3200,K bf16, t-major rows) @ W(2048,K bf16)^T
// Tile 128x256, BK=64. 8 waves as 2M x 4N, per-wave 64x64 output. Wave-row wm
// == one timestep -> BN stats wave-local. Writes NORMALIZED bf16 M.
//
// Pipeline (per-wave ledger, 6 global_load_lds per K-tile):
//   prologue: STAGE(0->buf0), STAGE(1->buf1), vmcnt(6) [t0 landed], barrier
//   iter t:  [t>0: vmcnt(6 if t+1<nk else 0)  -> tile t's 6 loads drained
//             s_barrier                        -> all waves' stages landed]
//            STAGE(t+2 -> buf[(t+2)%3])        (buf read at iter t-1; those
//                                               ds_reads retired before the
//                                               barrier above -> WAR safe)
//            ds_read frags from buf[t%3] ; 32 MFMA
// Loads get ~2 iters of landing window -> no drain-0 stall (T4, m218).
//
// LDS swizzle (T2, rule #21 both-sides): 16B col-block cb of row r stored at
// cb^(r&7); global SOURCE address pre-swizzled (gload_lds dest stays linear),
// ds_read applies the same XOR. Kills the 16-lane same-bank conflict.
__global__ __launch_bounds__(512, 2)
void gemm_bn_kernel(const u16* __restrict__ A, const u16* __restrict__ W,
                    u16* __restrict__ Mn, const float* __restrict__ g,
                    const float* __restrict__ be, int K) {
  __shared__ u16 As[3 * 128 * 64];   //  48 KiB
  __shared__ u16 Bs[3 * 256 * 64];   //  96 KiB
  const int tid = threadIdx.x;
  const int w = tid >> 6, l = tid & 63;
  const int wm = w >> 2, wn = w & 3;          // 2M x 4N waves
  const int bm = blockIdx.x, bn = blockIdx.y;
  f32x4 acc[4][4] = {};
  const u16* Ab = A + (size_t)bm * 128 * K;
  const u16* Wb = W + (size_t)bn * 256 * K;

  // staging geometry: 1 KiB LDS block = 8 rows x 64 cols bf16; lane l covers
  // row blk*8 + (l>>3), col-block (l&7). Swizzled source col-block:
  const int srow_in_blk = l >> 3;                 // 0..7
  const int scbs = (l & 7) ^ srow_in_blk;         // source 16B col-block
  // A: wave w stages blocks 2w, 2w+1 (rows 16w..16w+15)
  // B: wave w stages blocks 4w..4w+3 (rows 32w..32w+31)
  const int lr = l & 15;
  const int lkb = l >> 4;                          // 0..3 k-subblock
  const int nk = K >> 6;

#define STAGE(tt, bi) do {                                                   \
    const u16* ags = Ab + (tt) * 64 + scbs * 8;                              \
    const u16* wgs = Wb + (tt) * 64 + scbs * 8;                              \
    u16* al = As + (bi) * 8192;                                              \
    u16* bl = Bs + (bi) * 16384;                                             \
    GLDS16(ags + (size_t)((2*w    )*8 + srow_in_blk) * K, al + (2*w    )*512); \
    GLDS16(ags + (size_t)((2*w + 1)*8 + srow_in_blk) * K, al + (2*w + 1)*512); \
    GLDS16(wgs + (size_t)((4*w    )*8 + srow_in_blk) * K, bl + (4*w    )*512); \
    GLDS16(wgs + (size_t)((4*w + 1)*8 + srow_in_blk) * K, bl + (4*w + 1)*512); \
    GLDS16(wgs + (size_t)((4*w + 2)*8 + srow_in_blk) * K, bl + (4*w + 2)*512); \
    GLDS16(wgs + (size_t)((4*w + 3)*8 + srow_in_blk) * K, bl + (4*w + 3)*512); \
  } while (0)

  // prologue
  STAGE(0, 0);
  if (nk > 1) STAGE(1, 1);
  asm volatile("s_waitcnt vmcnt(6)" ::: "memory");
  __builtin_amdgcn_s_barrier();

  int cbuf = 0;
  for (int t = 0; t < nk; ++t) {
    if (t > 0) {
      if (t + 1 < nk) asm volatile("s_waitcnt vmcnt(6)" ::: "memory");
      else            asm volatile("s_waitcnt vmcnt(0)" ::: "memory");
      __builtin_amdgcn_s_barrier();
    }
    if (t + 2 < nk) {
      int nb = cbuf + 2; if (nb >= 3) nb -= 3;
      STAGE(t + 2, nb);
    }
    const u16* Ac = As + cbuf * 8192;
    const u16* Bc = Bs + cbuf * 16384;
#pragma unroll
    for (int kk = 0; kk < 2; ++kk) {
      bf16x8 af[4], bfr[4];
#pragma unroll
      for (int i = 0; i < 4; ++i) {
        int row = wm * 64 + i * 16 + lr;
        int cb  = (kk * 4 + lkb) ^ (lr & 7);
        af[i] = *(const bf16x8*)(Ac + row * 64 + cb * 8);
      }
#pragma unroll
      for (int j = 0; j < 4; ++j) {
        int row = wn * 64 + j * 16 + lr;
        int cb  = (kk * 4 + lkb) ^ (lr & 7);
        bfr[j] = *(const bf16x8*)(Bc + row * 64 + cb * 8);
      }
      __builtin_amdgcn_s_setprio(1);
#pragma unroll
      for (int i = 0; i < 4; ++i)
#pragma unroll
        for (int j = 0; j < 4; ++j)
          acc[i][j] = __builtin_amdgcn_mfma_f32_16x16x32_bf16(af[i], bfr[j], acc[i][j], 0, 0, 0);
      __builtin_amdgcn_s_setprio(0);
    }
    ++cbuf; if (cbuf >= 3) cbuf = 0;
  }
#undef STAGE

  // ---- fused BN epilogue: stats over the wave's 64 rows (= full batch of one t)
  const int lg = l >> 4;
  const int rbase = bm * 128 + wm * 64;
  const int cbase = bn * 256 + wn * 64;
#pragma unroll
  for (int j = 0; j < 4; ++j) {
    float s = 0.f, s2 = 0.f;
#pragma unroll
    for (int i = 0; i < 4; ++i)
#pragma unroll
      for (int r = 0; r < 4; ++r) { float v = acc[i][j][r]; s += v; s2 += v * v; }
    s  += __shfl_xor(s, 16);  s2 += __shfl_xor(s2, 16);
    s  += __shfl_xor(s, 32);  s2 += __shfl_xor(s2, 32);
    float mu  = s * (1.f / 64.f);
    float var = fmaxf(s2 * (1.f / 64.f) - mu * mu, 0.f);
    int col = cbase + j * 16 + lr;
    bool ok = col < NH;
    float gg = ok ? g[col]  : 0.f;
    float bb = ok ? be[col] : 0.f;
    float sc = rsqrtf(var + EPS) * gg;
#pragma unroll
    for (int i = 0; i < 4; ++i) {
      int row0 = rbase + i * 16 + lg * 4;
#pragma unroll
      for (int r = 0; r < 4; ++r)
        Mn[(size_t)(row0 + r) * HP + col] = f2bf((acc[i][j][r] - mu) * sc + bb);
    }
  }
}

// ---------------- IndRNN scan + residual (reads normalized bf16 M, t-major) ----------------
// thread = (b, h-pair). 65536 threads.
__global__ void scan_kernel(const u16* __restrict__ Mn, const float* __restrict__ u,
                            const float* __restrict__ res, float* __restrict__ out32,
                            int bmajor, u16* __restrict__ out16) {
  int tid = blockIdx.x * 256 + threadIdx.x;   // 64*1024
  int h2 = tid & 1023, b = tid >> 10;
  int h = h2 << 1;
  if (h >= NH) {
    if (out16) {
#pragma unroll 2
      for (int t = 0; t < NT; ++t)
        *(unsigned*)(out16 + (size_t)(t * NB + b) * HP + h) = 0u;
    }
    return;
  }
  float2 uu = *(const float2*)(u + h);
  float h0 = 0.f, h1 = 0.f;
  for (int t = 0; t < NT; ++t) {
    size_t idx = (size_t)(t * NB + b) * HP + h;
    unsigned mv = *(const unsigned*)(Mn + idx);
    float v0 = bf2f((u16)(mv & 0xffffu));
    float v1 = bf2f((u16)(mv >> 16));
    h0 = fmaxf(fmaf(uu.x, h0, v0), 0.f);
    h1 = fmaxf(fmaf(uu.y, h1, v1), 0.f);
    float o0 = h0, o1 = h1;
    if (res) {
      float2 rv = *(const float2*)(res + idx);
      o0 += rv.x; o1 += rv.y;
    }
    if (out32) {
      if (bmajor) {
        float2 ov = make_float2(o0, o1);
        *(float2*)(out32 + (size_t)(b * NT + t) * NH + h) = ov;
      } else {
        float2 ov = make_float2(o0, o1);
        *(float2*)(out32 + idx) = ov;
      }
    }
    if (out16) {
      unsigned pv = (unsigned)f2bf(o0) | ((unsigned)f2bf(o1) << 16);
      *(unsigned*)(out16 + idx) = pv;
    }
  }
}

// ---------------- orchestration ----------------
extern "C" void kernel_launch(void* const* d_in, const int* in_sizes, int n_in,
                              void* d_out, int out_size, void* d_ws, size_t ws_size,
                              hipStream_t stream) {
  const float* x   = (const float*)d_in[0];
  const float* W0  = (const float*)d_in[1];
  // d_in[2] = b0 (cancels in BN)
  const float* u0  = (const float*)d_in[3];
  const float* g0  = (const float*)d_in[4];
  const float* be0 = (const float*)d_in[5];
  const float* Ws  = (const float*)d_in[6];
  // d_in[7] = bs (cancels in BN)
  const float* us  = (const float*)d_in[8];
  const float* gs  = (const float*)d_in[9];
  const float* bes = (const float*)d_in[10];
  float* out = (float*)d_out;

  char* ws = (char*)d_ws;
  u16*   x16  = (u16*)  (ws + 0);           // 3200*256*2      = 1,638,400
  u16*   W016 = (u16*)  (ws + 1638400);     // 2048*256*2      = 1,048,576
  u16*   Ws16 = (u16*)  (ws + 2686976);     // 10*2048*2048*2  = 83,886,080
  u16*   Mbuf = (u16*)  (ws + 86573056);    // 3200*2048*2     = 13,107,200
  float* A32  = (float*)(ws + 99680256);    // 3200*2048*4     = 26,214,400
  u16*   A16  = (u16*)  (ws + 125894656);   // 3200*2048*2     = 13,107,200
  u16*   B16  = (u16*)  (ws + 139001856);   // 3200*2048*2     = 13,107,200

  // converts
  cvt_x_kernel <<<400,   256, 0, stream>>>(x, x16);
  cvt_w0_kernel<<<256,   256, 0, stream>>>(W0, W016);
  cvt_ws_kernel<<<20480, 256, 0, stream>>>(Ws, Ws16);

  dim3 ggrid(25, 8);

  // stem layer: x @ W0^T, K=256, fused BN
  gemm_bn_kernel<<<ggrid, 512, 0, stream>>>(x16, W016, Mbuf, g0, be0, NIN);
  scan_kernel   <<<256,   256, 0, stream>>>(Mbuf, u0, nullptr, A32, 0, A16);

  for (int l = 0; l < 10; ++l) {
    const u16* Ain = (l & 1) ? B16 : A16;
    gemm_bn_kernel<<<ggrid, 512, 0, stream>>>(Ain, Ws16 + (size_t)l * HP * HP, Mbuf,
                                              gs + (size_t)l * NH, bes + (size_t)l * NH, HP);
    const float* ul = us + (size_t)l * NH;
    if ((l & 1) == 0) {
      // first of pair: only bf16 activation needed for next GEMM
      scan_kernel<<<256, 256, 0, stream>>>(Mbuf, ul, nullptr, nullptr, 0, B16);
    } else if (l < 9) {
      // second of pair: add residual (A32), produce new A32 + A16
      scan_kernel<<<256, 256, 0, stream>>>(Mbuf, ul, A32, A32, 0, A16);
    } else {
      // last layer: add residual, write final output (b-major, stride 2000)
      scan_kernel<<<256, 256, 0, stream>>>(Mbuf, ul, A32, out, 1, nullptr);
    }
  }
}

// Round 5
// 832.919 us; speedup vs baseline: 1.2007x; 1.0069x over previous
//
#include <hip/hip_runtime.h>

typedef unsigned short u16;
typedef __attribute__((ext_vector_type(8))) short bf16x8;
typedef __attribute__((ext_vector_type(4))) float f32x4;

#define NB 64      // batch
#define NT 50      // time
#define NIN 256    // input dim
#define NH 2000    // hidden
#define HP 2048    // padded hidden
#define EPS 1e-4f

__device__ __forceinline__ u16 f2bf(float f) {
  unsigned x = __float_as_uint(f);
  x += 0x7fffu + ((x >> 16) & 1u);
  return (u16)(x >> 16);
}
__device__ __forceinline__ float bf2f(u16 u) {
  return __uint_as_float(((unsigned)u) << 16);
}

#define GLDS16(g, l) __builtin_amdgcn_global_load_lds( \
  (const __attribute__((address_space(1))) unsigned int*)(g), \
  (__attribute__((address_space(3))) unsigned int*)(l), 16, 0, 0)

// ---------------- converts (fp32 -> bf16, zero-padded) ----------------

// x: (B,T,IN) b-major -> x16 (3200,256) t-major rows (row = t*64+b).
__global__ void cvt_x_kernel(const float* __restrict__ x, u16* __restrict__ x16) {
  int tid = blockIdx.x * 256 + threadIdx.x;   // 102400
  int row = tid >> 5;                          // t*64+b
  int c8  = (tid & 31) << 3;
  int t = row >> 6, b = row & 63;
  const float* src = x + (size_t)(b * NT + t) * NIN + c8;
  float4 a = *(const float4*)src;
  float4 c = *(const float4*)(src + 4);
  union { u16 u[8]; uint4 v; } o;
  o.u[0]=f2bf(a.x); o.u[1]=f2bf(a.y); o.u[2]=f2bf(a.z); o.u[3]=f2bf(a.w);
  o.u[4]=f2bf(c.x); o.u[5]=f2bf(c.y); o.u[6]=f2bf(c.z); o.u[7]=f2bf(c.w);
  *(uint4*)(x16 + (size_t)row * NIN + c8) = o.v;
}

// W0: (2000,256) -> (2048,256) bf16, rows >=2000 zero.
__global__ void cvt_w0_kernel(const float* __restrict__ W0, u16* __restrict__ W16) {
  int tid = blockIdx.x * 256 + threadIdx.x;
  int r = tid >> 5;
  int c8 = (tid & 31) << 3;
  union { u16 u[8]; uint4 v; } o;
  if (r < NH) {
    const float* src = W0 + (size_t)r * NIN + c8;
    float4 a = *(const float4*)src;
    float4 b = *(const float4*)(src + 4);
    o.u[0]=f2bf(a.x); o.u[1]=f2bf(a.y); o.u[2]=f2bf(a.z); o.u[3]=f2bf(a.w);
    o.u[4]=f2bf(b.x); o.u[5]=f2bf(b.y); o.u[6]=f2bf(b.z); o.u[7]=f2bf(b.w);
  } else {
    o.v = make_uint4(0,0,0,0);
  }
  *(uint4*)(W16 + (size_t)tid * 8) = o.v;
}

// Ws: (10,2000,2000) -> (10,2048,2048) bf16, pad zero.
__global__ void cvt_ws_kernel(const float* __restrict__ Ws, u16* __restrict__ W16) {
  int tid = blockIdx.x * 256 + threadIdx.x;
  int l  = tid >> 19;
  int r  = (tid >> 8) & 2047;
  int c8 = (tid & 255) << 3;
  union { u16 u[8]; uint4 v; } o;
  if (r < NH && c8 < NH) {
    const float* src = Ws + (size_t)l * (NH * NH) + (size_t)r * NH + c8;
    float4 a = *(const float4*)src;
    float4 b = *(const float4*)(src + 4);
    o.u[0]=f2bf(a.x); o.u[1]=f2bf(a.y); o.u[2]=f2bf(a.z); o.u[3]=f2bf(a.w);
    o.u[4]=f2bf(b.x); o.u[5]=f2bf(b.y); o.u[6]=f2bf(b.z); o.u[7]=f2bf(b.w);
  } else {
    o.v = make_uint4(0,0,0,0);
  }
  *(uint4*)(W16 + (size_t)tid * 8) = o.v;
}

// ---------------- GEMM + fused BatchNorm (triple-buffered, counted vmcnt,
//                  XCD-panel-affine block swizzle) ----------------
// C(3200,2048) = A(3200,K bf16, t-major rows) @ W(2048,K bf16)^T
// Tile 128x256, BK=64. 8 waves as 2M x 4N, per-wave 64x64 output. Wave-row wm
// == one timestep -> BN stats wave-local. Writes NORMALIZED bf16 M.
//
// XCD swizzle: 1-D grid of 200, bn = bid&7, bm = bid>>3 (bijective, 200%8==0).
// HW maps bid%8 -> XCD, so all 25 blocks sharing a 1 MB B-panel land on ONE
// XCD: B-panel becomes L2-resident (4 MB/XCD), off-XCD traffic/GEMM 305->113MB.
//
// Pipeline (per-wave ledger, 6 global_load_lds per K-tile):
//   prologue: STAGE(0->buf0), STAGE(1->buf1), vmcnt(6) [t0 landed], barrier
//   iter t:  [t>0: vmcnt(6 if t+1<nk else 0) -> tile t's loads drained;
//             s_barrier -> all waves' stages landed]
//            STAGE(t+2 -> buf[(t+2)%3])  (WAR-safe: that buf's readers
//            retired before the barrier above)
//            ds_read frags from buf[t%3] ; 32 MFMA
// LDS swizzle (T2, rule #21 both-sides): 16B col-block cb of row r stored at
// cb^(r&7); global SOURCE pre-swizzled (gload_lds dest linear), ds_read
// applies the same XOR.
__global__ __launch_bounds__(512, 2)
void gemm_bn_kernel(const u16* __restrict__ A, const u16* __restrict__ W,
                    u16* __restrict__ Mn, const float* __restrict__ g,
                    const float* __restrict__ be, int K) {
  __shared__ u16 As[3 * 128 * 64];   //  48 KiB
  __shared__ u16 Bs[3 * 256 * 64];   //  96 KiB
  const int tid = threadIdx.x;
  const int w = tid >> 6, l = tid & 63;
  const int wm = w >> 2, wn = w & 3;          // 2M x 4N waves
  const int bid = blockIdx.x;
  const int bn = bid & 7;                     // same-bn -> same XCD (bid%8)
  const int bm = bid >> 3;                    // 0..24
  f32x4 acc[4][4] = {};
  const u16* Ab = A + (size_t)bm * 128 * K;
  const u16* Wb = W + (size_t)bn * 256 * K;

  // staging geometry: 1 KiB LDS block = 8 rows x 64 cols bf16; lane l covers
  // row blk*8 + (l>>3), col-block (l&7). Swizzled source col-block:
  const int srow_in_blk = l >> 3;                 // 0..7
  const int scbs = (l & 7) ^ srow_in_blk;         // source 16B col-block
  const int lr = l & 15;
  const int lkb = l >> 4;                          // 0..3 k-subblock
  const int nk = K >> 6;

#define STAGE(tt, bi) do {                                                   \
    const u16* ags = Ab + (tt) * 64 + scbs * 8;                              \
    const u16* wgs = Wb + (tt) * 64 + scbs * 8;                              \
    u16* al = As + (bi) * 8192;                                              \
    u16* bl = Bs + (bi) * 16384;                                             \
    GLDS16(ags + (size_t)((2*w    )*8 + srow_in_blk) * K, al + (2*w    )*512); \
    GLDS16(ags + (size_t)((2*w + 1)*8 + srow_in_blk) * K, al + (2*w + 1)*512); \
    GLDS16(wgs + (size_t)((4*w    )*8 + srow_in_blk) * K, bl + (4*w    )*512); \
    GLDS16(wgs + (size_t)((4*w + 1)*8 + srow_in_blk) * K, bl + (4*w + 1)*512); \
    GLDS16(wgs + (size_t)((4*w + 2)*8 + srow_in_blk) * K, bl + (4*w + 2)*512); \
    GLDS16(wgs + (size_t)((4*w + 3)*8 + srow_in_blk) * K, bl + (4*w + 3)*512); \
  } while (0)

  // prologue
  STAGE(0, 0);
  if (nk > 1) STAGE(1, 1);
  asm volatile("s_waitcnt vmcnt(6)" ::: "memory");
  __builtin_amdgcn_s_barrier();

  int cbuf = 0;
  for (int t = 0; t < nk; ++t) {
    if (t > 0) {
      if (t + 1 < nk) asm volatile("s_waitcnt vmcnt(6)" ::: "memory");
      else            asm volatile("s_waitcnt vmcnt(0)" ::: "memory");
      __builtin_amdgcn_s_barrier();
    }
    if (t + 2 < nk) {
      int nb = cbuf + 2; if (nb >= 3) nb -= 3;
      STAGE(t + 2, nb);
    }
    const u16* Ac = As + cbuf * 8192;
    const u16* Bc = Bs + cbuf * 16384;
#pragma unroll
    for (int kk = 0; kk < 2; ++kk) {
      bf16x8 af[4], bfr[4];
#pragma unroll
      for (int i = 0; i < 4; ++i) {
        int row = wm * 64 + i * 16 + lr;
        int cb  = (kk * 4 + lkb) ^ (lr & 7);
        af[i] = *(const bf16x8*)(Ac + row * 64 + cb * 8);
      }
#pragma unroll
      for (int j = 0; j < 4; ++j) {
        int row = wn * 64 + j * 16 + lr;
        int cb  = (kk * 4 + lkb) ^ (lr & 7);
        bfr[j] = *(const bf16x8*)(Bc + row * 64 + cb * 8);
      }
      __builtin_amdgcn_s_setprio(1);
#pragma unroll
      for (int i = 0; i < 4; ++i)
#pragma unroll
        for (int j = 0; j < 4; ++j)
          acc[i][j] = __builtin_amdgcn_mfma_f32_16x16x32_bf16(af[i], bfr[j], acc[i][j], 0, 0, 0);
      __builtin_amdgcn_s_setprio(0);
    }
    ++cbuf; if (cbuf >= 3) cbuf = 0;
  }
#undef STAGE

  // ---- fused BN epilogue: stats over the wave's 64 rows (= full batch of one t)
  const int lg = l >> 4;
  const int rbase = bm * 128 + wm * 64;
  const int cbase = bn * 256 + wn * 64;
#pragma unroll
  for (int j = 0; j < 4; ++j) {
    float s = 0.f, s2 = 0.f;
#pragma unroll
    for (int i = 0; i < 4; ++i)
#pragma unroll
      for (int r = 0; r < 4; ++r) { float v = acc[i][j][r]; s += v; s2 += v * v; }
    s  += __shfl_xor(s, 16);  s2 += __shfl_xor(s2, 16);
    s  += __shfl_xor(s, 32);  s2 += __shfl_xor(s2, 32);
    float mu  = s * (1.f / 64.f);
    float var = fmaxf(s2 * (1.f / 64.f) - mu * mu, 0.f);
    int col = cbase + j * 16 + lr;
    bool ok = col < NH;
    float gg = ok ? g[col]  : 0.f;
    float bb = ok ? be[col] : 0.f;
    float sc = rsqrtf(var + EPS) * gg;
#pragma unroll
    for (int i = 0; i < 4; ++i) {
      int row0 = rbase + i * 16 + lg * 4;
#pragma unroll
      for (int r = 0; r < 4; ++r)
        Mn[(size_t)(row0 + r) * HP + col] = f2bf((acc[i][j][r] - mu) * sc + bb);
    }
  }
}

// ---------------- IndRNN scan + residual (reads normalized bf16 M, t-major) ----------------
// thread = (b, h-pair). 65536 threads.
__global__ void scan_kernel(const u16* __restrict__ Mn, const float* __restrict__ u,
                            const float* __restrict__ res, float* __restrict__ out32,
                            int bmajor, u16* __restrict__ out16) {
  int tid = blockIdx.x * 256 + threadIdx.x;   // 64*1024
  int h2 = tid & 1023, b = tid >> 10;
  int h = h2 << 1;
  if (h >= NH) {
    if (out16) {
#pragma unroll 2
      for (int t = 0; t < NT; ++t)
        *(unsigned*)(out16 + (size_t)(t * NB + b) * HP + h) = 0u;
    }
    return;
  }
  float2 uu = *(const float2*)(u + h);
  float h0 = 0.f, h1 = 0.f;
  for (int t = 0; t < NT; ++t) {
    size_t idx = (size_t)(t * NB + b) * HP + h;
    unsigned mv = *(const unsigned*)(Mn + idx);
    float v0 = bf2f((u16)(mv & 0xffffu));
    float v1 = bf2f((u16)(mv >> 16));
    h0 = fmaxf(fmaf(uu.x, h0, v0), 0.f);
    h1 = fmaxf(fmaf(uu.y, h1, v1), 0.f);
    float o0 = h0, o1 = h1;
    if (res) {
      float2 rv = *(const float2*)(res + idx);
      o0 += rv.x; o1 += rv.y;
    }
    if (out32) {
      if (bmajor) {
        float2 ov = make_float2(o0, o1);
        *(float2*)(out32 + (size_t)(b * NT + t) * NH + h) = ov;
      } else {
        float2 ov = make_float2(o0, o1);
        *(float2*)(out32 + idx) = ov;
      }
    }
    if (out16) {
      unsigned pv = (unsigned)f2bf(o0) | ((unsigned)f2bf(o1) << 16);
      *(unsigned*)(out16 + idx) = pv;
    }
  }
}

// ---------------- orchestration ----------------
extern "C" void kernel_launch(void* const* d_in, const int* in_sizes, int n_in,
                              void* d_out, int out_size, void* d_ws, size_t ws_size,
                              hipStream_t stream) {
  const float* x   = (const float*)d_in[0];
  const float* W0  = (const float*)d_in[1];
  // d_in[2] = b0 (cancels in BN)
  const float* u0  = (const float*)d_in[3];
  const float* g0  = (const float*)d_in[4];
  const float* be0 = (const float*)d_in[5];
  const float* Ws  = (const float*)d_in[6];
  // d_in[7] = bs (cancels in BN)
  const float* us  = (const float*)d_in[8];
  const float* gs  = (const float*)d_in[9];
  const float* bes = (const float*)d_in[10];
  float* out = (float*)d_out;

  char* ws = (char*)d_ws;
  u16*   x16  = (u16*)  (ws + 0);           // 3200*256*2      = 1,638,400
  u16*   W016 = (u16*)  (ws + 1638400);     // 2048*256*2      = 1,048,576
  u16*   Ws16 = (u16*)  (ws + 2686976);     // 10*2048*2048*2  = 83,886,080
  u16*   Mbuf = (u16*)  (ws + 86573056);    // 3200*2048*2     = 13,107,200
  float* A32  = (float*)(ws + 99680256);    // 3200*2048*4     = 26,214,400
  u16*   A16  = (u16*)  (ws + 125894656);   // 3200*2048*2     = 13,107,200
  u16*   B16  = (u16*)  (ws + 139001856);   // 3200*2048*2     = 13,107,200

  // converts
  cvt_x_kernel <<<400,   256, 0, stream>>>(x, x16);
  cvt_w0_kernel<<<256,   256, 0, stream>>>(W0, W016);
  cvt_ws_kernel<<<20480, 256, 0, stream>>>(Ws, Ws16);

  // stem layer: x @ W0^T, K=256, fused BN
  gemm_bn_kernel<<<200, 512, 0, stream>>>(x16, W016, Mbuf, g0, be0, NIN);
  scan_kernel   <<<256, 256, 0, stream>>>(Mbuf, u0, nullptr, A32, 0, A16);

  for (int l = 0; l < 10; ++l) {
    const u16* Ain = (l & 1) ? B16 : A16;
    gemm_bn_kernel<<<200, 512, 0, stream>>>(Ain, Ws16 + (size_t)l * HP * HP, Mbuf,
                                            gs + (size_t)l * NH, bes + (size_t)l * NH, HP);
    const float* ul = us + (size_t)l * NH;
    if ((l & 1) == 0) {
      // first of pair: only bf16 activation needed for next GEMM
      scan_kernel<<<256, 256, 0, stream>>>(Mbuf, ul, nullptr, nullptr, 0, B16);
    } else if (l < 9) {
      // second of pair: add residual (A32), produce new A32 + A16
      scan_kernel<<<256, 256, 0, stream>>>(Mbuf, ul, A32, A32, 0, A16);
    } else {
      // last layer: add residual, write final output (b-major, stride 2000)
      scan_kernel<<<256, 256, 0, stream>>>(Mbuf, ul, A32, out, 1, nullptr);
    }
  }
}

// Round 6
// 644.982 us; speedup vs baseline: 1.5506x; 1.2914x over previous
//
#include <hip/hip_runtime.h>

typedef unsigned short u16;
typedef __attribute__((ext_vector_type(8))) short bf16x8;
typedef __attribute__((ext_vector_type(4))) float f32x4;

#define NB 64      // batch
#define NT 50      // time
#define NIN 256    // input dim
#define NH 2000    // hidden
#define HP 2048    // padded hidden
#define EPS 1e-4f

__device__ __forceinline__ u16 f2bf(float f) {
  unsigned x = __float_as_uint(f);
  x += 0x7fffu + ((x >> 16) & 1u);
  return (u16)(x >> 16);
}
__device__ __forceinline__ float bf2f(u16 u) {
  return __uint_as_float(((unsigned)u) << 16);
}

#define GLDS16(g, l) __builtin_amdgcn_global_load_lds( \
  (const __attribute__((address_space(1))) unsigned int*)(g), \
  (__attribute__((address_space(3))) unsigned int*)(l), 16, 0, 0)

// ---------------- converts (fp32 -> bf16, zero-padded) ----------------

// x: (B,T,IN) b-major -> x16 (3200,256) t-major rows (row = t*64+b).
__global__ void cvt_x_kernel(const float* __restrict__ x, u16* __restrict__ x16) {
  int tid = blockIdx.x * 256 + threadIdx.x;   // 102400
  int row = tid >> 5;                          // t*64+b
  int c8  = (tid & 31) << 3;
  int t = row >> 6, b = row & 63;
  const float* src = x + (size_t)(b * NT + t) * NIN + c8;
  float4 a = *(const float4*)src;
  float4 c = *(const float4*)(src + 4);
  union { u16 u[8]; uint4 v; } o;
  o.u[0]=f2bf(a.x); o.u[1]=f2bf(a.y); o.u[2]=f2bf(a.z); o.u[3]=f2bf(a.w);
  o.u[4]=f2bf(c.x); o.u[5]=f2bf(c.y); o.u[6]=f2bf(c.z); o.u[7]=f2bf(c.w);
  *(uint4*)(x16 + (size_t)row * NIN + c8) = o.v;
}

// W0: (2000,256) -> (2048,256) bf16, rows >=2000 zero.
__global__ void cvt_w0_kernel(const float* __restrict__ W0, u16* __restrict__ W16) {
  int tid = blockIdx.x * 256 + threadIdx.x;
  int r = tid >> 5;
  int c8 = (tid & 31) << 3;
  union { u16 u[8]; uint4 v; } o;
  if (r < NH) {
    const float* src = W0 + (size_t)r * NIN + c8;
    float4 a = *(const float4*)src;
    float4 b = *(const float4*)(src + 4);
    o.u[0]=f2bf(a.x); o.u[1]=f2bf(a.y); o.u[2]=f2bf(a.z); o.u[3]=f2bf(a.w);
    o.u[4]=f2bf(b.x); o.u[5]=f2bf(b.y); o.u[6]=f2bf(b.z); o.u[7]=f2bf(b.w);
  } else {
    o.v = make_uint4(0,0,0,0);
  }
  *(uint4*)(W16 + (size_t)tid * 8) = o.v;
}

// Ws: (10,2000,2000) -> (10,2048,2048) bf16, pad zero.
__global__ void cvt_ws_kernel(const float* __restrict__ Ws, u16* __restrict__ W16) {
  int tid = blockIdx.x * 256 + threadIdx.x;
  int l  = tid >> 19;
  int r  = (tid >> 8) & 2047;
  int c8 = (tid & 255) << 3;
  union { u16 u[8]; uint4 v; } o;
  if (r < NH && c8 < NH) {
    const float* src = Ws + (size_t)l * (NH * NH) + (size_t)r * NH + c8;
    float4 a = *(const float4*)src;
    float4 b = *(const float4*)(src + 4);
    o.u[0]=f2bf(a.x); o.u[1]=f2bf(a.y); o.u[2]=f2bf(a.z); o.u[3]=f2bf(a.w);
    o.u[4]=f2bf(b.x); o.u[5]=f2bf(b.y); o.u[6]=f2bf(b.z); o.u[7]=f2bf(b.w);
  } else {
    o.v = make_uint4(0,0,0,0);
  }
  *(uint4*)(W16 + (size_t)tid * 8) = o.v;
}

// ---------------- GEMM + fused BatchNorm (unchanged from R5) ----------------
__global__ __launch_bounds__(512, 2)
void gemm_bn_kernel(const u16* __restrict__ A, const u16* __restrict__ W,
                    u16* __restrict__ Mn, const float* __restrict__ g,
                    const float* __restrict__ be, int K) {
  __shared__ u16 As[3 * 128 * 64];   //  48 KiB
  __shared__ u16 Bs[3 * 256 * 64];   //  96 KiB
  const int tid = threadIdx.x;
  const int w = tid >> 6, l = tid & 63;
  const int wm = w >> 2, wn = w & 3;          // 2M x 4N waves
  const int bid = blockIdx.x;
  const int bn = bid & 7;                     // same-bn -> same XCD (bid%8)
  const int bm = bid >> 3;                    // 0..24
  f32x4 acc[4][4] = {};
  const u16* Ab = A + (size_t)bm * 128 * K;
  const u16* Wb = W + (size_t)bn * 256 * K;

  const int srow_in_blk = l >> 3;                 // 0..7
  const int scbs = (l & 7) ^ srow_in_blk;         // source 16B col-block (pre-swizzled)
  const int lr = l & 15;
  const int lkb = l >> 4;                          // 0..3 k-subblock
  const int nk = K >> 6;

#define STAGE(tt, bi) do {                                                   \
    const u16* ags = Ab + (tt) * 64 + scbs * 8;                              \
    const u16* wgs = Wb + (tt) * 64 + scbs * 8;                              \
    u16* al = As + (bi) * 8192;                                              \
    u16* bl = Bs + (bi) * 16384;                                             \
    GLDS16(ags + (size_t)((2*w    )*8 + srow_in_blk) * K, al + (2*w    )*512); \
    GLDS16(ags + (size_t)((2*w + 1)*8 + srow_in_blk) * K, al + (2*w + 1)*512); \
    GLDS16(wgs + (size_t)((4*w    )*8 + srow_in_blk) * K, bl + (4*w    )*512); \
    GLDS16(wgs + (size_t)((4*w + 1)*8 + srow_in_blk) * K, bl + (4*w + 1)*512); \
    GLDS16(wgs + (size_t)((4*w + 2)*8 + srow_in_blk) * K, bl + (4*w + 2)*512); \
    GLDS16(wgs + (size_t)((4*w + 3)*8 + srow_in_blk) * K, bl + (4*w + 3)*512); \
  } while (0)

  STAGE(0, 0);
  if (nk > 1) STAGE(1, 1);
  asm volatile("s_waitcnt vmcnt(6)" ::: "memory");
  __builtin_amdgcn_s_barrier();

  int cbuf = 0;
  for (int t = 0; t < nk; ++t) {
    if (t > 0) {
      if (t + 1 < nk) asm volatile("s_waitcnt vmcnt(6)" ::: "memory");
      else            asm volatile("s_waitcnt vmcnt(0)" ::: "memory");
      __builtin_amdgcn_s_barrier();
    }
    if (t + 2 < nk) {
      int nb = cbuf + 2; if (nb >= 3) nb -= 3;
      STAGE(t + 2, nb);
    }
    const u16* Ac = As + cbuf * 8192;
    const u16* Bc = Bs + cbuf * 16384;
#pragma unroll
    for (int kk = 0; kk < 2; ++kk) {
      bf16x8 af[4], bfr[4];
#pragma unroll
      for (int i = 0; i < 4; ++i) {
        int row = wm * 64 + i * 16 + lr;
        int cb  = (kk * 4 + lkb) ^ (lr & 7);
        af[i] = *(const bf16x8*)(Ac + row * 64 + cb * 8);
      }
#pragma unroll
      for (int j = 0; j < 4; ++j) {
        int row = wn * 64 + j * 16 + lr;
        int cb  = (kk * 4 + lkb) ^ (lr & 7);
        bfr[j] = *(const bf16x8*)(Bc + row * 64 + cb * 8);
      }
      __builtin_amdgcn_s_setprio(1);
#pragma unroll
      for (int i = 0; i < 4; ++i)
#pragma unroll
        for (int j = 0; j < 4; ++j)
          acc[i][j] = __builtin_amdgcn_mfma_f32_16x16x32_bf16(af[i], bfr[j], acc[i][j], 0, 0, 0);
      __builtin_amdgcn_s_setprio(0);
    }
    ++cbuf; if (cbuf >= 3) cbuf = 0;
  }
#undef STAGE

  const int lg = l >> 4;
  const int rbase = bm * 128 + wm * 64;
  const int cbase = bn * 256 + wn * 64;
#pragma unroll
  for (int j = 0; j < 4; ++j) {
    float s = 0.f, s2 = 0.f;
#pragma unroll
    for (int i = 0; i < 4; ++i)
#pragma unroll
      for (int r = 0; r < 4; ++r) { float v = acc[i][j][r]; s += v; s2 += v * v; }
    s  += __shfl_xor(s, 16);  s2 += __shfl_xor(s2, 16);
    s  += __shfl_xor(s, 32);  s2 += __shfl_xor(s2, 32);
    float mu  = s * (1.f / 64.f);
    float var = fmaxf(s2 * (1.f / 64.f) - mu * mu, 0.f);
    int col = cbase + j * 16 + lr;
    bool ok = col < NH;
    float gg = ok ? g[col]  : 0.f;
    float bb = ok ? be[col] : 0.f;
    float sc = rsqrtf(var + EPS) * gg;
#pragma unroll
    for (int i = 0; i < 4; ++i) {
      int row0 = rbase + i * 16 + lg * 4;
#pragma unroll
      for (int r = 0; r < 4; ++r)
        Mn[(size_t)(row0 + r) * HP + col] = f2bf((acc[i][j][r] - mu) * sc + bb);
    }
  }
}

// ---------------- IndRNN scans: all-prefetch, branch-free variants ----------------
// Key structural change: all 50 M-loads are issued BEFORE the recurrence
// (static-index full unroll -> registers, 50 loads in flight per wave) so the
// sequential h-update never waits on memory. Thread = (b, h-pair).

// pad columns h>=NH of a bf16 activation buffer -> 0 (GEMM reads them)
__device__ __forceinline__ void pad16(u16* out16, int b, int h) {
#pragma unroll
  for (int t = 0; t < NT; ++t)
    *(unsigned*)(out16 + (size_t)(t * NB + b) * HP + h) = 0u;
}

// first-of-pair: Mn -> bf16 activation only
__global__ void scan_a_kernel(const u16* __restrict__ Mn, const float* __restrict__ u,
                              u16* __restrict__ out16) {
  int tid = blockIdx.x * 256 + threadIdx.x;   // 65536
  int h2 = tid & 1023, b = tid >> 10;
  int h = h2 << 1;
  if (h >= NH) { pad16(out16, b, h); return; }
  unsigned mv[NT];
#pragma unroll
  for (int t = 0; t < NT; ++t)
    mv[t] = *(const unsigned*)(Mn + (size_t)(t * NB + b) * HP + h);
  float2 uu = *(const float2*)(u + h);
  float h0 = 0.f, h1 = 0.f;
#pragma unroll
  for (int t = 0; t < NT; ++t) {
    h0 = fmaxf(fmaf(uu.x, h0, bf2f((u16)(mv[t] & 0xffffu))), 0.f);
    h1 = fmaxf(fmaf(uu.y, h1, bf2f((u16)(mv[t] >> 16))), 0.f);
    *(unsigned*)(out16 + (size_t)(t * NB + b) * HP + h) =
        (unsigned)f2bf(h0) | ((unsigned)f2bf(h1) << 16);
  }
}

// second-of-pair / stem: out = scan(+res); writes f32 residual + bf16 activation
template<bool HASRES>
__global__ void scan_b_kernel(const u16* __restrict__ Mn, const float* __restrict__ u,
                              const float* __restrict__ res, float* __restrict__ out32,
                              u16* __restrict__ out16) {
  int tid = blockIdx.x * 256 + threadIdx.x;   // 65536
  int h2 = tid & 1023, b = tid >> 10;
  int h = h2 << 1;
  if (h >= NH) { pad16(out16, b, h); return; }
  unsigned mv[NT];
#pragma unroll
  for (int t = 0; t < NT; ++t)
    mv[t] = *(const unsigned*)(Mn + (size_t)(t * NB + b) * HP + h);
  float2 rv[NT];
  if (HASRES) {
#pragma unroll
    for (int t = 0; t < NT; ++t)
      rv[t] = *(const float2*)(res + (size_t)(t * NB + b) * HP + h);
  }
  float2 uu = *(const float2*)(u + h);
  float h0 = 0.f, h1 = 0.f;
#pragma unroll
  for (int t = 0; t < NT; ++t) {
    h0 = fmaxf(fmaf(uu.x, h0, bf2f((u16)(mv[t] & 0xffffu))), 0.f);
    h1 = fmaxf(fmaf(uu.y, h1, bf2f((u16)(mv[t] >> 16))), 0.f);
    float o0 = h0, o1 = h1;
    if (HASRES) { o0 += rv[t].x; o1 += rv[t].y; }
    size_t idx = (size_t)(t * NB + b) * HP + h;
    *(float2*)(out32 + idx) = make_float2(o0, o1);
    *(unsigned*)(out16 + idx) = (unsigned)f2bf(o0) | ((unsigned)f2bf(o1) << 16);
  }
}

// last layer: out = scan + res, written b-major f32 (stride NH)
__global__ void scan_c_kernel(const u16* __restrict__ Mn, const float* __restrict__ u,
                              const float* __restrict__ res, float* __restrict__ out) {
  int tid = blockIdx.x * 256 + threadIdx.x;   // 65536
  int h2 = tid & 1023, b = tid >> 10;
  int h = h2 << 1;
  if (h >= NH) return;
  unsigned mv[NT];
#pragma unroll
  for (int t = 0; t < NT; ++t)
    mv[t] = *(const unsigned*)(Mn + (size_t)(t * NB + b) * HP + h);
  float2 rv[NT];
#pragma unroll
  for (int t = 0; t < NT; ++t)
    rv[t] = *(const float2*)(res + (size_t)(t * NB + b) * HP + h);
  float2 uu = *(const float2*)(u + h);
  float h0 = 0.f, h1 = 0.f;
#pragma unroll
  for (int t = 0; t < NT; ++t) {
    h0 = fmaxf(fmaf(uu.x, h0, bf2f((u16)(mv[t] & 0xffffu))), 0.f);
    h1 = fmaxf(fmaf(uu.y, h1, bf2f((u16)(mv[t] >> 16))), 0.f);
    *(float2*)(out + (size_t)(b * NT + t) * NH + h) =
        make_float2(h0 + rv[t].x, h1 + rv[t].y);
  }
}

// ---------------- orchestration ----------------
extern "C" void kernel_launch(void* const* d_in, const int* in_sizes, int n_in,
                              void* d_out, int out_size, void* d_ws, size_t ws_size,
                              hipStream_t stream) {
  const float* x   = (const float*)d_in[0];
  const float* W0  = (const float*)d_in[1];
  // d_in[2] = b0 (cancels in BN)
  const float* u0  = (const float*)d_in[3];
  const float* g0  = (const float*)d_in[4];
  const float* be0 = (const float*)d_in[5];
  const float* Ws  = (const float*)d_in[6];
  // d_in[7] = bs (cancels in BN)
  const float* us  = (const float*)d_in[8];
  const float* gs  = (const float*)d_in[9];
  const float* bes = (const float*)d_in[10];
  float* out = (float*)d_out;

  char* ws = (char*)d_ws;
  u16*   x16  = (u16*)  (ws + 0);           // 3200*256*2      = 1,638,400
  u16*   W016 = (u16*)  (ws + 1638400);     // 2048*256*2      = 1,048,576
  u16*   Ws16 = (u16*)  (ws + 2686976);     // 10*2048*2048*2  = 83,886,080
  u16*   Mbuf = (u16*)  (ws + 86573056);    // 3200*2048*2     = 13,107,200
  float* A32  = (float*)(ws + 99680256);    // 3200*2048*4     = 26,214,400
  u16*   A16  = (u16*)  (ws + 125894656);   // 3200*2048*2     = 13,107,200
  u16*   B16  = (u16*)  (ws + 139001856);   // 3200*2048*2     = 13,107,200

  // converts
  cvt_x_kernel <<<400,   256, 0, stream>>>(x, x16);
  cvt_w0_kernel<<<256,   256, 0, stream>>>(W0, W016);
  cvt_ws_kernel<<<20480, 256, 0, stream>>>(Ws, Ws16);

  // stem layer: x @ W0^T, K=256, fused BN; scan writes A32 (residual base) + A16
  gemm_bn_kernel<<<200, 512, 0, stream>>>(x16, W016, Mbuf, g0, be0, NIN);
  scan_b_kernel<false><<<256, 256, 0, stream>>>(Mbuf, u0, nullptr, A32, A16);

  for (int l = 0; l < 10; ++l) {
    const u16* Ain = (l & 1) ? B16 : A16;
    gemm_bn_kernel<<<200, 512, 0, stream>>>(Ain, Ws16 + (size_t)l * HP * HP, Mbuf,
                                            gs + (size_t)l * NH, bes + (size_t)l * NH, HP);
    const float* ul = us + (size_t)l * NH;
    if ((l & 1) == 0) {
      scan_a_kernel<<<256, 256, 0, stream>>>(Mbuf, ul, B16);
    } else if (l < 9) {
      scan_b_kernel<true><<<256, 256, 0, stream>>>(Mbuf, ul, A32, A32, A16);
    } else {
      scan_c_kernel<<<256, 256, 0, stream>>>(Mbuf, ul, A32, out);
    }
  }
}

// Round 7
// 617.584 us; speedup vs baseline: 1.6194x; 1.0444x over previous
//
#include <hip/hip_runtime.h>

typedef unsigned short u16;
typedef __attribute__((ext_vector_type(8))) short bf16x8;
typedef __attribute__((ext_vector_type(4))) float f32x4;

#define NB 64      // batch
#define NT 50      // time
#define NIN 256    // input dim
#define NH 2000    // hidden
#define HP 2048    // padded hidden
#define EPS 1e-4f

__device__ __forceinline__ u16 f2bf(float f) {
  unsigned x = __float_as_uint(f);
  x += 0x7fffu + ((x >> 16) & 1u);
  return (u16)(x >> 16);
}
__device__ __forceinline__ float bf2f(u16 u) {
  return __uint_as_float(((unsigned)u) << 16);
}

#define GLDS16(g, l) __builtin_amdgcn_global_load_lds( \
  (const __attribute__((address_space(1))) unsigned int*)(g), \
  (__attribute__((address_space(3))) unsigned int*)(l), 16, 0, 0)

// ---------------- converts (fp32 -> bf16, zero-padded) ----------------

// x: (B,T,IN) b-major -> x16 (3200,256) t-major rows (row = t*64+b).
__global__ void cvt_x_kernel(const float* __restrict__ x, u16* __restrict__ x16) {
  int tid = blockIdx.x * 256 + threadIdx.x;   // 102400
  int row = tid >> 5;                          // t*64+b
  int c8  = (tid & 31) << 3;
  int t = row >> 6, b = row & 63;
  const float* src = x + (size_t)(b * NT + t) * NIN + c8;
  float4 a = *(const float4*)src;
  float4 c = *(const float4*)(src + 4);
  union { u16 u[8]; uint4 v; } o;
  o.u[0]=f2bf(a.x); o.u[1]=f2bf(a.y); o.u[2]=f2bf(a.z); o.u[3]=f2bf(a.w);
  o.u[4]=f2bf(c.x); o.u[5]=f2bf(c.y); o.u[6]=f2bf(c.z); o.u[7]=f2bf(c.w);
  *(uint4*)(x16 + (size_t)row * NIN + c8) = o.v;
}

// W0: (2000,256) -> (2048,256) bf16, rows >=2000 zero.
__global__ void cvt_w0_kernel(const float* __restrict__ W0, u16* __restrict__ W16) {
  int tid = blockIdx.x * 256 + threadIdx.x;
  int r = tid >> 5;
  int c8 = (tid & 31) << 3;
  union { u16 u[8]; uint4 v; } o;
  if (r < NH) {
    const float* src = W0 + (size_t)r * NIN + c8;
    float4 a = *(const float4*)src;
    float4 b = *(const float4*)(src + 4);
    o.u[0]=f2bf(a.x); o.u[1]=f2bf(a.y); o.u[2]=f2bf(a.z); o.u[3]=f2bf(a.w);
    o.u[4]=f2bf(b.x); o.u[5]=f2bf(b.y); o.u[6]=f2bf(b.z); o.u[7]=f2bf(b.w);
  } else {
    o.v = make_uint4(0,0,0,0);
  }
  *(uint4*)(W16 + (size_t)tid * 8) = o.v;
}

// Ws: (10,2000,2000) -> (10,2048,2048) bf16, pad zero.
__global__ void cvt_ws_kernel(const float* __restrict__ Ws, u16* __restrict__ W16) {
  int tid = blockIdx.x * 256 + threadIdx.x;
  int l  = tid >> 19;
  int r  = (tid >> 8) & 2047;
  int c8 = (tid & 255) << 3;
  union { u16 u[8]; uint4 v; } o;
  if (r < NH && c8 < NH) {
    const float* src = Ws + (size_t)l * (NH * NH) + (size_t)r * NH + c8;
    float4 a = *(const float4*)src;
    float4 b = *(const float4*)(src + 4);
    o.u[0]=f2bf(a.x); o.u[1]=f2bf(a.y); o.u[2]=f2bf(a.z); o.u[3]=f2bf(a.w);
    o.u[4]=f2bf(b.x); o.u[5]=f2bf(b.y); o.u[6]=f2bf(b.z); o.u[7]=f2bf(b.w);
  } else {
    o.v = make_uint4(0,0,0,0);
  }
  *(uint4*)(W16 + (size_t)tid * 8) = o.v;
}

// ---------------- GEMM + fused BatchNorm (high-occupancy 128x128) ----------------
// C(3200,2048) = A(3200,K bf16, t-major rows) @ W(2048,K bf16)^T
// Tile 128x128, BK=32, 8 waves as 2M x 4N -> per-wave 64x32 (wave covers all
// 64 batch rows of one timestep -> BN stats wave-local). 400 blocks x 512 thr
// = 3.1 waves/SIMD avg (2x R5) — occupancy is the lever this round.
// Triple-buffered LDS (48 KiB -> 2 blocks/CU co-resident), counted vmcnt(2)
// with a 2-iteration landing window. XCD-affine: XCD x owns B-panels {x, x+8}
// (1 MB -> L2-resident). LDS XOR-swizzle both-sides (rule #21): 16B col-block
// cb of row r at cb^(r&3); source pre-swizzled, ds_read applies same XOR.
__global__ __launch_bounds__(512, 4)
void gemm_bn_kernel(const u16* __restrict__ A, const u16* __restrict__ W,
                    u16* __restrict__ Mn, const float* __restrict__ g,
                    const float* __restrict__ be, int K) {
  __shared__ u16 As[3 * 128 * 32];   // 24 KiB
  __shared__ u16 Bs[3 * 128 * 32];   // 24 KiB
  const int tid = threadIdx.x;
  const int w = tid >> 6, l = tid & 63;
  const int wm = w >> 2, wn = w & 3;          // 2M x 4N waves, wave = 64x32
  const int bid = blockIdx.x;
  const int xcd = bid & 7;
  const int r0  = bid >> 3;                   // 0..49
  const int hi  = r0 >= 25;
  const int bn  = xcd + (hi << 3);            // 0..15, same-XCD panel pair
  const int bm  = r0 - 25 * hi;               // 0..24
  f32x4 acc[4][2] = {};
  const u16* Ab = A + (size_t)bm * 128 * K;
  const u16* Wb = W + (size_t)bn * 128 * K;

  // staging: 1 load = 16 rows x 64B; wave w stages A-rows/B-rows 16w..16w+15.
  const int srow = l >> 2;                    // 0..15 row within 16-row block
  const int scb  = (l & 3) ^ (srow & 3);      // pre-swizzled source col-block
  const size_t goff = (size_t)(w * 16 + srow) * K + scb * 8;
  const int lr  = l & 15;
  const int lkb = l >> 4;                     // 0..3 k-subblock
  const int nk  = K >> 5;

#define STAGE(tt, bi) do {                                        \
    GLDS16(Ab + goff + (tt) * 32, As + (bi) * 4096 + w * 512);    \
    GLDS16(Wb + goff + (tt) * 32, Bs + (bi) * 4096 + w * 512);    \
  } while (0)

  // prologue: tiles 0,1 in flight (2 loads/wave each)
  STAGE(0, 0);
  STAGE(1, 1);
  asm volatile("s_waitcnt vmcnt(2)" ::: "memory");   // tile 0 landed
  __builtin_amdgcn_s_barrier();

  int cbuf = 0;
  for (int t = 0; t < nk; ++t) {
    if (t > 0) {
      if (t + 1 < nk) asm volatile("s_waitcnt vmcnt(2)" ::: "memory");
      else            asm volatile("s_waitcnt vmcnt(0)" ::: "memory");
      __builtin_amdgcn_s_barrier();
    }
    if (t + 2 < nk) {
      int nb = cbuf + 2; if (nb >= 3) nb -= 3;
      STAGE(t + 2, nb);              // WAR-safe: that buf's readers retired
    }
    const u16* Ac = As + cbuf * 4096;
    const u16* Bc = Bs + cbuf * 4096;
    bf16x8 af[4], bfr[2];
    const int cb = (lkb ^ (lr & 3)) * 8;
#pragma unroll
    for (int i = 0; i < 4; ++i)
      af[i] = *(const bf16x8*)(Ac + (wm * 64 + i * 16 + lr) * 32 + cb);
#pragma unroll
    for (int j = 0; j < 2; ++j)
      bfr[j] = *(const bf16x8*)(Bc + (wn * 32 + j * 16 + lr) * 32 + cb);
    __builtin_amdgcn_s_setprio(1);
#pragma unroll
    for (int i = 0; i < 4; ++i)
#pragma unroll
      for (int j = 0; j < 2; ++j)
        acc[i][j] = __builtin_amdgcn_mfma_f32_16x16x32_bf16(af[i], bfr[j], acc[i][j], 0, 0, 0);
    __builtin_amdgcn_s_setprio(0);
    ++cbuf; if (cbuf >= 3) cbuf = 0;
  }
#undef STAGE

  // ---- fused BN epilogue: stats over the wave's 64 rows (= full batch of one t)
  const int lg = l >> 4;
  const int rbase = bm * 128 + wm * 64;
  const int cbase = bn * 128 + wn * 32;
#pragma unroll
  for (int j = 0; j < 2; ++j) {
    float s = 0.f, s2 = 0.f;
#pragma unroll
    for (int i = 0; i < 4; ++i)
#pragma unroll
      for (int r = 0; r < 4; ++r) { float v = acc[i][j][r]; s += v; s2 += v * v; }
    s  += __shfl_xor(s, 16);  s2 += __shfl_xor(s2, 16);
    s  += __shfl_xor(s, 32);  s2 += __shfl_xor(s2, 32);
    float mu  = s * (1.f / 64.f);
    float var = fmaxf(s2 * (1.f / 64.f) - mu * mu, 0.f);
    int col = cbase + j * 16 + lr;
    bool ok = col < NH;
    float gg = ok ? g[col]  : 0.f;
    float bb = ok ? be[col] : 0.f;
    float sc = rsqrtf(var + EPS) * gg;
#pragma unroll
    for (int i = 0; i < 4; ++i) {
      int row0 = rbase + i * 16 + lg * 4;
#pragma unroll
      for (int r = 0; r < 4; ++r)
        Mn[(size_t)(row0 + r) * HP + col] = f2bf((acc[i][j][r] - mu) * sc + bb);
    }
  }
}

// ---------------- IndRNN scans: all-prefetch, branch-free variants ----------------
__device__ __forceinline__ void pad16(u16* out16, int b, int h) {
#pragma unroll
  for (int t = 0; t < NT; ++t)
    *(unsigned*)(out16 + (size_t)(t * NB + b) * HP + h) = 0u;
}

// first-of-pair: Mn -> bf16 activation only
__global__ void scan_a_kernel(const u16* __restrict__ Mn, const float* __restrict__ u,
                              u16* __restrict__ out16) {
  int tid = blockIdx.x * 256 + threadIdx.x;   // 65536
  int h2 = tid & 1023, b = tid >> 10;
  int h = h2 << 1;
  if (h >= NH) { pad16(out16, b, h); return; }
  unsigned mv[NT];
#pragma unroll
  for (int t = 0; t < NT; ++t)
    mv[t] = *(const unsigned*)(Mn + (size_t)(t * NB + b) * HP + h);
  float2 uu = *(const float2*)(u + h);
  float h0 = 0.f, h1 = 0.f;
#pragma unroll
  for (int t = 0; t < NT; ++t) {
    h0 = fmaxf(fmaf(uu.x, h0, bf2f((u16)(mv[t] & 0xffffu))), 0.f);
    h1 = fmaxf(fmaf(uu.y, h1, bf2f((u16)(mv[t] >> 16))), 0.f);
    *(unsigned*)(out16 + (size_t)(t * NB + b) * HP + h) =
        (unsigned)f2bf(h0) | ((unsigned)f2bf(h1) << 16);
  }
}

// second-of-pair / stem: out = scan(+res); writes f32 residual + bf16 activation
template<bool HASRES>
__global__ void scan_b_kernel(const u16* __restrict__ Mn, const float* __restrict__ u,
                              const float* __restrict__ res, float* __restrict__ out32,
                              u16* __restrict__ out16) {
  int tid = blockIdx.x * 256 + threadIdx.x;   // 65536
  int h2 = tid & 1023, b = tid >> 10;
  int h = h2 << 1;
  if (h >= NH) { pad16(out16, b, h); return; }
  unsigned mv[NT];
#pragma unroll
  for (int t = 0; t < NT; ++t)
    mv[t] = *(const unsigned*)(Mn + (size_t)(t * NB + b) * HP + h);
  float2 rv[NT];
  if (HASRES) {
#pragma unroll
    for (int t = 0; t < NT; ++t)
      rv[t] = *(const float2*)(res + (size_t)(t * NB + b) * HP + h);
  }
  float2 uu = *(const float2*)(u + h);
  float h0 = 0.f, h1 = 0.f;
#pragma unroll
  for (int t = 0; t < NT; ++t) {
    h0 = fmaxf(fmaf(uu.x, h0, bf2f((u16)(mv[t] & 0xffffu))), 0.f);
    h1 = fmaxf(fmaf(uu.y, h1, bf2f((u16)(mv[t] >> 16))), 0.f);
    float o0 = h0, o1 = h1;
    if (HASRES) { o0 += rv[t].x; o1 += rv[t].y; }
    size_t idx = (size_t)(t * NB + b) * HP + h;
    *(float2*)(out32 + idx) = make_float2(o0, o1);
    *(unsigned*)(out16 + idx) = (unsigned)f2bf(o0) | ((unsigned)f2bf(o1) << 16);
  }
}

// last layer: out = scan + res, written b-major f32 (stride NH)
__global__ void scan_c_kernel(const u16* __restrict__ Mn, const float* __restrict__ u,
                              const float* __restrict__ res, float* __restrict__ out) {
  int tid = blockIdx.x * 256 + threadIdx.x;   // 65536
  int h2 = tid & 1023, b = tid >> 10;
  int h = h2 << 1;
  if (h >= NH) return;
  unsigned mv[NT];
#pragma unroll
  for (int t = 0; t < NT; ++t)
    mv[t] = *(const unsigned*)(Mn + (size_t)(t * NB + b) * HP + h);
  float2 rv[NT];
#pragma unroll
  for (int t = 0; t < NT; ++t)
    rv[t] = *(const float2*)(res + (size_t)(t * NB + b) * HP + h);
  float2 uu = *(const float2*)(u + h);
  float h0 = 0.f, h1 = 0.f;
#pragma unroll
  for (int t = 0; t < NT; ++t) {
    h0 = fmaxf(fmaf(uu.x, h0, bf2f((u16)(mv[t] & 0xffffu))), 0.f);
    h1 = fmaxf(fmaf(uu.y, h1, bf2f((u16)(mv[t] >> 16))), 0.f);
    *(float2*)(out + (size_t)(b * NT + t) * NH + h) =
        make_float2(h0 + rv[t].x, h1 + rv[t].y);
  }
}

// ---------------- orchestration ----------------
extern "C" void kernel_launch(void* const* d_in, const int* in_sizes, int n_in,
                              void* d_out, int out_size, void* d_ws, size_t ws_size,
                              hipStream_t stream) {
  const float* x   = (const float*)d_in[0];
  const float* W0  = (const float*)d_in[1];
  // d_in[2] = b0 (cancels in BN)
  const float* u0  = (const float*)d_in[3];
  const float* g0  = (const float*)d_in[4];
  const float* be0 = (const float*)d_in[5];
  const float* Ws  = (const float*)d_in[6];
  // d_in[7] = bs (cancels in BN)
  const float* us  = (const float*)d_in[8];
  const float* gs  = (const float*)d_in[9];
  const float* bes = (const float*)d_in[10];
  float* out = (float*)d_out;

  char* ws = (char*)d_ws;
  u16*   x16  = (u16*)  (ws + 0);           // 3200*256*2      = 1,638,400
  u16*   W016 = (u16*)  (ws + 1638400);     // 2048*256*2      = 1,048,576
  u16*   Ws16 = (u16*)  (ws + 2686976);     // 10*2048*2048*2  = 83,886,080
  u16*   Mbuf = (u16*)  (ws + 86573056);    // 3200*2048*2     = 13,107,200
  float* A32  = (float*)(ws + 99680256);    // 3200*2048*4     = 26,214,400
  u16*   A16  = (u16*)  (ws + 125894656);   // 3200*2048*2     = 13,107,200
  u16*   B16  = (u16*)  (ws + 139001856);   // 3200*2048*2     = 13,107,200

  // converts
  cvt_x_kernel <<<400,   256, 0, stream>>>(x, x16);
  cvt_w0_kernel<<<256,   256, 0, stream>>>(W0, W016);
  cvt_ws_kernel<<<20480, 256, 0, stream>>>(Ws, Ws16);

  // stem layer: x @ W0^T, K=256, fused BN; scan writes A32 (residual base) + A16
  gemm_bn_kernel<<<400, 512, 0, stream>>>(x16, W016, Mbuf, g0, be0, NIN);
  scan_b_kernel<false><<<256, 256, 0, stream>>>(Mbuf, u0, nullptr, A32, A16);

  for (int l = 0; l < 10; ++l) {
    const u16* Ain = (l & 1) ? B16 : A16;
    gemm_bn_kernel<<<400, 512, 0, stream>>>(Ain, Ws16 + (size_t)l * HP * HP, Mbuf,
                                            gs + (size_t)l * NH, bes + (size_t)l * NH, HP);
    const float* ul = us + (size_t)l * NH;
    if ((l & 1) == 0) {
      scan_a_kernel<<<256, 256, 0, stream>>>(Mbuf, ul, B16);
    } else if (l < 9) {
      scan_b_kernel<true><<<256, 256, 0, stream>>>(Mbuf, ul, A32, A32, A16);
    } else {
      scan_c_kernel<<<256, 256, 0, stream>>>(Mbuf, ul, A32, out);
    }
  }
}

// Round 8
// 603.437 us; speedup vs baseline: 1.6573x; 1.0234x over previous
//
#include <hip/hip_runtime.h>

typedef unsigned short u16;
typedef __attribute__((ext_vector_type(8))) short bf16x8;
typedef __attribute__((ext_vector_type(4))) float f32x4;

#define NB 64      // batch
#define NT 50      // time
#define NIN 256    // input dim
#define NH 2000    // hidden
#define HP 2048    // padded hidden
#define EPS 1e-4f

__device__ __forceinline__ u16 f2bf(float f) {
  unsigned x = __float_as_uint(f);
  x += 0x7fffu + ((x >> 16) & 1u);
  return (u16)(x >> 16);
}
__device__ __forceinline__ float bf2f(u16 u) {
  return __uint_as_float(((unsigned)u) << 16);
}

#define GLDS16(g, l) __builtin_amdgcn_global_load_lds( \
  (const __attribute__((address_space(1))) unsigned int*)(g), \
  (__attribute__((address_space(3))) unsigned int*)(l), 16, 0, 0)

// ---------------- converts (fp32 -> bf16, zero-padded) ----------------

// x: (B,T,IN) b-major -> x16 (3200,256) t-major rows (row = t*64+b).
__global__ void cvt_x_kernel(const float* __restrict__ x, u16* __restrict__ x16) {
  int tid = blockIdx.x * 256 + threadIdx.x;   // 102400
  int row = tid >> 5;                          // t*64+b
  int c8  = (tid & 31) << 3;
  int t = row >> 6, b = row & 63;
  const float* src = x + (size_t)(b * NT + t) * NIN + c8;
  float4 a = *(const float4*)src;
  float4 c = *(const float4*)(src + 4);
  union { u16 u[8]; uint4 v; } o;
  o.u[0]=f2bf(a.x); o.u[1]=f2bf(a.y); o.u[2]=f2bf(a.z); o.u[3]=f2bf(a.w);
  o.u[4]=f2bf(c.x); o.u[5]=f2bf(c.y); o.u[6]=f2bf(c.z); o.u[7]=f2bf(c.w);
  *(uint4*)(x16 + (size_t)row * NIN + c8) = o.v;
}

// W0: (2000,256) -> (2048,256) bf16, rows >=2000 zero.
__global__ void cvt_w0_kernel(const float* __restrict__ W0, u16* __restrict__ W16) {
  int tid = blockIdx.x * 256 + threadIdx.x;
  int r = tid >> 5;
  int c8 = (tid & 31) << 3;
  union { u16 u[8]; uint4 v; } o;
  if (r < NH) {
    const float* src = W0 + (size_t)r * NIN + c8;
    float4 a = *(const float4*)src;
    float4 b = *(const float4*)(src + 4);
    o.u[0]=f2bf(a.x); o.u[1]=f2bf(a.y); o.u[2]=f2bf(a.z); o.u[3]=f2bf(a.w);
    o.u[4]=f2bf(b.x); o.u[5]=f2bf(b.y); o.u[6]=f2bf(b.z); o.u[7]=f2bf(b.w);
  } else {
    o.v = make_uint4(0,0,0,0);
  }
  *(uint4*)(W16 + (size_t)tid * 8) = o.v;
}

// Ws: (10,2000,2000) -> (10,2048,2048) bf16, pad zero.
__global__ void cvt_ws_kernel(const float* __restrict__ Ws, u16* __restrict__ W16) {
  int tid = blockIdx.x * 256 + threadIdx.x;
  int l  = tid >> 19;
  int r  = (tid >> 8) & 2047;
  int c8 = (tid & 255) << 3;
  union { u16 u[8]; uint4 v; } o;
  if (r < NH && c8 < NH) {
    const float* src = Ws + (size_t)l * (NH * NH) + (size_t)r * NH + c8;
    float4 a = *(const float4*)src;
    float4 b = *(const float4*)(src + 4);
    o.u[0]=f2bf(a.x); o.u[1]=f2bf(a.y); o.u[2]=f2bf(a.z); o.u[3]=f2bf(a.w);
    o.u[4]=f2bf(b.x); o.u[5]=f2bf(b.y); o.u[6]=f2bf(b.z); o.u[7]=f2bf(b.w);
  } else {
    o.v = make_uint4(0,0,0,0);
  }
  *(uint4*)(W16 + (size_t)tid * 8) = o.v;
}

// ---------------- GEMM + fused BatchNorm (128x128, depth-3 prefetch) ----------------
// C(3200,2048) = A(3200,K bf16, t-major rows) @ W(2048,K bf16)^T
// Tile 128x128, BK=32, 8 waves as 2M x 4N -> per-wave 64x32 (wave covers all
// 64 batch rows of one timestep -> BN stats wave-local). 400 blocks.
// Quad-buffered LDS (64 KiB, 2 blocks/CU), prefetch depth 3: iter t stages
// tile t+3, waits vmcnt(4) (vmcnt retires in ISSUE order -> oldest tile's 2
// loads drained), giving ~2 iterations (~800-1000 cy) landing window — enough
// for L3-latency (~900 cy) A-panel fetches. Tail: vmcnt(2)/vmcnt(0).
// XCD-affine: XCD x owns B-panels {x, x+8} (L2-resident). LDS XOR-swizzle
// both-sides (rule #21): source pre-swizzled, ds_read same XOR.
__global__ __launch_bounds__(512, 4)
void gemm_bn_kernel(const u16* __restrict__ A, const u16* __restrict__ W,
                    u16* __restrict__ Mn, const float* __restrict__ g,
                    const float* __restrict__ be, int K) {
  __shared__ u16 As[4 * 128 * 32];   // 32 KiB
  __shared__ u16 Bs[4 * 128 * 32];   // 32 KiB
  const int tid = threadIdx.x;
  const int w = tid >> 6, l = tid & 63;
  const int wm = w >> 2, wn = w & 3;          // 2M x 4N waves, wave = 64x32
  const int bid = blockIdx.x;
  const int xcd = bid & 7;
  const int r0  = bid >> 3;                   // 0..49
  const int hi  = r0 >= 25;
  const int bn  = xcd + (hi << 3);            // 0..15, same-XCD panel pair
  const int bm  = r0 - 25 * hi;               // 0..24
  f32x4 acc[4][2] = {};
  const u16* Ab = A + (size_t)bm * 128 * K;
  const u16* Wb = W + (size_t)bn * 128 * K;

  // staging: 1 load = 16 rows x 64B; wave w stages A-rows/B-rows 16w..16w+15.
  const int srow = l >> 2;                    // 0..15 row within 16-row block
  const int scb  = (l & 3) ^ (srow & 3);      // pre-swizzled source col-block
  const size_t goff = (size_t)(w * 16 + srow) * K + scb * 8;
  const int lr  = l & 15;
  const int lkb = l >> 4;                     // 0..3 k-subblock
  const int nk  = K >> 5;

#define STAGE(tt, bi) do {                                        \
    GLDS16(Ab + goff + (tt) * 32, As + (bi) * 4096 + w * 512);    \
    GLDS16(Wb + goff + (tt) * 32, Bs + (bi) * 4096 + w * 512);    \
  } while (0)

  // prologue: tiles 0,1,2 in flight (2 loads/wave each -> 6 outstanding)
  STAGE(0, 0);
  STAGE(1, 1);
  STAGE(2, 2);
  asm volatile("s_waitcnt vmcnt(4)" ::: "memory");   // tile 0 landed
  __builtin_amdgcn_s_barrier();

  for (int t = 0; t < nk; ++t) {
    if (t > 0) {
      int rem = nk - 1 - t;
      if (rem >= 2)      asm volatile("s_waitcnt vmcnt(4)" ::: "memory");
      else if (rem == 1) asm volatile("s_waitcnt vmcnt(2)" ::: "memory");
      else               asm volatile("s_waitcnt vmcnt(0)" ::: "memory");
      __builtin_amdgcn_s_barrier();
    }
    if (t + 3 < nk) {
      STAGE(t + 3, (t + 3) & 3);     // WAR-safe: buf (t+3)&3 was read at
    }                                 // iter t-1; readers retired pre-barrier
    const u16* Ac = As + (t & 3) * 4096;
    const u16* Bc = Bs + (t & 3) * 4096;
    bf16x8 af[4], bfr[2];
    const int cb = (lkb ^ (lr & 3)) * 8;
#pragma unroll
    for (int i = 0; i < 4; ++i)
      af[i] = *(const bf16x8*)(Ac + (wm * 64 + i * 16 + lr) * 32 + cb);
#pragma unroll
    for (int j = 0; j < 2; ++j)
      bfr[j] = *(const bf16x8*)(Bc + (wn * 32 + j * 16 + lr) * 32 + cb);
    __builtin_amdgcn_s_setprio(1);
#pragma unroll
    for (int i = 0; i < 4; ++i)
#pragma unroll
      for (int j = 0; j < 2; ++j)
        acc[i][j] = __builtin_amdgcn_mfma_f32_16x16x32_bf16(af[i], bfr[j], acc[i][j], 0, 0, 0);
    __builtin_amdgcn_s_setprio(0);
  }
#undef STAGE

  // ---- fused BN epilogue: stats over the wave's 64 rows (= full batch of one t)
  const int lg = l >> 4;
  const int rbase = bm * 128 + wm * 64;
  const int cbase = bn * 128 + wn * 32;
#pragma unroll
  for (int j = 0; j < 2; ++j) {
    float s = 0.f, s2 = 0.f;
#pragma unroll
    for (int i = 0; i < 4; ++i)
#pragma unroll
      for (int r = 0; r < 4; ++r) { float v = acc[i][j][r]; s += v; s2 += v * v; }
    s  += __shfl_xor(s, 16);  s2 += __shfl_xor(s2, 16);
    s  += __shfl_xor(s, 32);  s2 += __shfl_xor(s2, 32);
    float mu  = s * (1.f / 64.f);
    float var = fmaxf(s2 * (1.f / 64.f) - mu * mu, 0.f);
    int col = cbase + j * 16 + lr;
    bool ok = col < NH;
    float gg = ok ? g[col]  : 0.f;
    float bb = ok ? be[col] : 0.f;
    float sc = rsqrtf(var + EPS) * gg;
#pragma unroll
    for (int i = 0; i < 4; ++i) {
      int row0 = rbase + i * 16 + lg * 4;
#pragma unroll
      for (int r = 0; r < 4; ++r)
        Mn[(size_t)(row0 + r) * HP + col] = f2bf((acc[i][j][r] - mu) * sc + bb);
    }
  }
}

// ---------------- IndRNN scans: all-prefetch, branch-free ----------------
// Residual is stored in bf16, UNIFIED with the activation buffer (the next
// GEMM consumed bf16 anyway; keeping a separate f32 copy only served the
// skip-add). scan_b writes ONE buffer that is both next-GEMM input and the
// residual. Thread = (b, h-pair); all 50 M-loads issued before the recurrence.

__device__ __forceinline__ void pad16(u16* out16, int b, int h) {
#pragma unroll
  for (int t = 0; t < NT; ++t)
    *(unsigned*)(out16 + (size_t)(t * NB + b) * HP + h) = 0u;
}

// first-of-pair: Mn -> bf16 activation only
__global__ void scan_a_kernel(const u16* __restrict__ Mn, const float* __restrict__ u,
                              u16* __restrict__ out16) {
  int tid = blockIdx.x * 256 + threadIdx.x;   // 65536
  int h2 = tid & 1023, b = tid >> 10;
  int h = h2 << 1;
  if (h >= NH) { pad16(out16, b, h); return; }
  unsigned mv[NT];
#pragma unroll
  for (int t = 0; t < NT; ++t)
    mv[t] = *(const unsigned*)(Mn + (size_t)(t * NB + b) * HP + h);
  float2 uu = *(const float2*)(u + h);
  float h0 = 0.f, h1 = 0.f;
#pragma unroll
  for (int t = 0; t < NT; ++t) {
    h0 = fmaxf(fmaf(uu.x, h0, bf2f((u16)(mv[t] & 0xffffu))), 0.f);
    h1 = fmaxf(fmaf(uu.y, h1, bf2f((u16)(mv[t] >> 16))), 0.f);
    *(unsigned*)(out16 + (size_t)(t * NB + b) * HP + h) =
        (unsigned)f2bf(h0) | ((unsigned)f2bf(h1) << 16);
  }
}

// second-of-pair / stem: out16 = bf16(scan [+ res16]) — activation AND residual
template<bool HASRES>
__global__ void scan_b_kernel(const u16* __restrict__ Mn, const float* __restrict__ u,
                              const u16* __restrict__ res16, u16* __restrict__ out16) {
  int tid = blockIdx.x * 256 + threadIdx.x;   // 65536
  int h2 = tid & 1023, b = tid >> 10;
  int h = h2 << 1;
  if (h >= NH) { pad16(out16, b, h); return; }
  unsigned mv[NT];
#pragma unroll
  for (int t = 0; t < NT; ++t)
    mv[t] = *(const unsigned*)(Mn + (size_t)(t * NB + b) * HP + h);
  unsigned rv[NT];
  if (HASRES) {
#pragma unroll
    for (int t = 0; t < NT; ++t)
      rv[t] = *(const unsigned*)(res16 + (size_t)(t * NB + b) * HP + h);
  }
  float2 uu = *(const float2*)(u + h);
  float h0 = 0.f, h1 = 0.f;
#pragma unroll
  for (int t = 0; t < NT; ++t) {
    h0 = fmaxf(fmaf(uu.x, h0, bf2f((u16)(mv[t] & 0xffffu))), 0.f);
    h1 = fmaxf(fmaf(uu.y, h1, bf2f((u16)(mv[t] >> 16))), 0.f);
    float o0 = h0, o1 = h1;
    if (HASRES) {
      o0 += bf2f((u16)(rv[t] & 0xffffu));
      o1 += bf2f((u16)(rv[t] >> 16));
    }
    *(unsigned*)(out16 + (size_t)(t * NB + b) * HP + h) =
        (unsigned)f2bf(o0) | ((unsigned)f2bf(o1) << 16);
  }
}

// last layer: out = scan + res16, written b-major f32 (stride NH)
__global__ void scan_c_kernel(const u16* __restrict__ Mn, const float* __restrict__ u,
                              const u16* __restrict__ res16, float* __restrict__ out) {
  int tid = blockIdx.x * 256 + threadIdx.x;   // 65536
  int h2 = tid & 1023, b = tid >> 10;
  int h = h2 << 1;
  if (h >= NH) return;
  unsigned mv[NT];
#pragma unroll
  for (int t = 0; t < NT; ++t)
    mv[t] = *(const unsigned*)(Mn + (size_t)(t * NB + b) * HP + h);
  unsigned rv[NT];
#pragma unroll
  for (int t = 0; t < NT; ++t)
    rv[t] = *(const unsigned*)(res16 + (size_t)(t * NB + b) * HP + h);
  float2 uu = *(const float2*)(u + h);
  float h0 = 0.f, h1 = 0.f;
#pragma unroll
  for (int t = 0; t < NT; ++t) {
    h0 = fmaxf(fmaf(uu.x, h0, bf2f((u16)(mv[t] & 0xffffu))), 0.f);
    h1 = fmaxf(fmaf(uu.y, h1, bf2f((u16)(mv[t] >> 16))), 0.f);
    *(float2*)(out + (size_t)(b * NT + t) * NH + h) =
        make_float2(h0 + bf2f((u16)(rv[t] & 0xffffu)),
                    h1 + bf2f((u16)(rv[t] >> 16)));
  }
}

// ---------------- orchestration ----------------
extern "C" void kernel_launch(void* const* d_in, const int* in_sizes, int n_in,
                              void* d_out, int out_size, void* d_ws, size_t ws_size,
                              hipStream_t stream) {
  const float* x   = (const float*)d_in[0];
  const float* W0  = (const float*)d_in[1];
  // d_in[2] = b0 (cancels in BN)
  const float* u0  = (const float*)d_in[3];
  const float* g0  = (const float*)d_in[4];
  const float* be0 = (const float*)d_in[5];
  const float* Ws  = (const float*)d_in[6];
  // d_in[7] = bs (cancels in BN)
  const float* us  = (const float*)d_in[8];
  const float* gs  = (const float*)d_in[9];
  const float* bes = (const float*)d_in[10];
  float* out = (float*)d_out;

  char* ws = (char*)d_ws;
  u16*   x16  = (u16*)  (ws + 0);           // 3200*256*2      = 1,638,400
  u16*   W016 = (u16*)  (ws + 1638400);     // 2048*256*2      = 1,048,576
  u16*   Ws16 = (u16*)  (ws + 2686976);     // 10*2048*2048*2  = 83,886,080
  u16*   Mbuf = (u16*)  (ws + 86573056);    // 3200*2048*2     = 13,107,200
  u16*   A16  = (u16*)  (ws + 99680256);    // 3200*2048*2     = 13,107,200 (activation+residual)
  u16*   B16  = (u16*)  (ws + 112787456);   // 3200*2048*2     = 13,107,200

  // converts
  cvt_x_kernel <<<400,   256, 0, stream>>>(x, x16);
  cvt_w0_kernel<<<256,   256, 0, stream>>>(W0, W016);
  cvt_ws_kernel<<<20480, 256, 0, stream>>>(Ws, Ws16);

  // stem layer: x @ W0^T, K=256, fused BN; scan writes A16 (activation+residual)
  gemm_bn_kernel<<<400, 512, 0, stream>>>(x16, W016, Mbuf, g0, be0, NIN);
  scan_b_kernel<false><<<256, 256, 0, stream>>>(Mbuf, u0, nullptr, A16);

  for (int l = 0; l < 10; ++l) {
    const u16* Ain = (l & 1) ? B16 : A16;
    gemm_bn_kernel<<<400, 512, 0, stream>>>(Ain, Ws16 + (size_t)l * HP * HP, Mbuf,
                                            gs + (size_t)l * NH, bes + (size_t)l * NH, HP);
    const float* ul = us + (size_t)l * NH;
    if ((l & 1) == 0) {
      scan_a_kernel<<<256, 256, 0, stream>>>(Mbuf, ul, B16);
    } else if (l < 9) {
      // new A16 = bf16(scan + old A16): next activation AND next residual
      scan_b_kernel<true><<<256, 256, 0, stream>>>(Mbuf, ul, A16, A16);
    } else {
      scan_c_kernel<<<256, 256, 0, stream>>>(Mbuf, ul, A16, out);
    }
  }
}